// Round 13
// baseline (425.450 us; speedup 1.0000x reference)
//
#include <hip/hip_runtime.h>
#include <hip/hip_cooperative_groups.h>
#include <hip/hip_fp16.h>
#include <math.h>

namespace cg = cooperative_groups;

#define DT_F 0.1f

// scal[] slots
#define SC_Z     0
#define SC_RMEAN 1
#define SC_KMULT 2
#define SC_OP    3
#define SC_OPSTR 4
#define SC_SM    5

typedef __attribute__((ext_vector_type(8))) short short8;
typedef __attribute__((ext_vector_type(4))) float f32x4;

// ---------------------------------------------------------------- helpers

__device__ __forceinline__ float gelu_f(float x) {
    return 0.5f * x * (1.0f + erff(x * 0.7071067811865475f));
}

__device__ __forceinline__ unsigned short f2bf_rne(float f) {
    union { float f; unsigned u; } v; v.f = f;
    unsigned x = v.u;
    unsigned r = x + 0x7fffu + ((x >> 16) & 1u);
    return (unsigned short)(r >> 16);
}

__device__ __forceinline__ unsigned rotl32(unsigned v, int d) {
    return (v << d) | (v >> (32 - d));
}

// JAX threefry2x32, 20 rounds
__device__ __forceinline__ void threefry2x32(unsigned k0, unsigned k1,
                                             unsigned x0, unsigned x1,
                                             unsigned& o0, unsigned& o1) {
    unsigned k2 = k0 ^ k1 ^ 0x1BD11BDAu;
    x0 += k0; x1 += k1;
    const int r0[4] = {13, 15, 26, 6};
    const int r1[4] = {17, 29, 16, 24};
#pragma unroll
    for (int g = 0; g < 5; ++g) {
        const int* R = (g & 1) ? r1 : r0;
#pragma unroll
        for (int q = 0; q < 4; ++q) { x0 += x1; x1 = rotl32(x1, R[q]); x1 ^= x0; }
        unsigned a, b;
        switch (g) {
            case 0:  a = k1; b = k2 + 1u; break;
            case 1:  a = k2; b = k0 + 2u; break;
            case 2:  a = k0; b = k1 + 3u; break;
            case 3:  a = k1; b = k2 + 4u; break;
            default: a = k2; b = k0 + 5u; break;
        }
        x0 += a; x1 += b;
    }
    o0 = x0; o1 = x1;
}

// XLA ErfInv32 (Giles polynomial)
__device__ __forceinline__ float erfinv_xla(float x) {
    float w = -log1pf(-x * x);
    float p;
    if (w < 5.0f) {
        w -= 2.5f;
        p = 2.81022636e-08f;
        p = fmaf(p, w, 3.43273939e-07f);
        p = fmaf(p, w, -3.5233877e-06f);
        p = fmaf(p, w, -4.39150654e-06f);
        p = fmaf(p, w, 0.00021858087f);
        p = fmaf(p, w, -0.00125372503f);
        p = fmaf(p, w, -0.00417768164f);
        p = fmaf(p, w, 0.246640727f);
        p = fmaf(p, w, 1.50140941f);
    } else {
        w = sqrtf(w) - 3.0f;
        p = -0.000200214257f;
        p = fmaf(p, w, 0.000100950558f);
        p = fmaf(p, w, 0.00134934322f);
        p = fmaf(p, w, -0.00367342844f);
        p = fmaf(p, w, 0.00573950773f);
        p = fmaf(p, w, -0.0076224613f);
        p = fmaf(p, w, 0.00943887047f);
        p = fmaf(p, w, 1.00167406f);
        p = fmaf(p, w, 2.83297682f);
    }
    return p * x;
}

// jax.random.normal(fold_in(key(42), li), (1024,256)) element at flat index
__device__ __forceinline__ float jax_normal_elem(unsigned fk0, unsigned fk1, unsigned flat) {
    const unsigned HALF = 131072u;  // 1024*256/2
    unsigned idx = (flat < HALF) ? flat : (flat - HALF);
    unsigned o0, o1;
    threefry2x32(fk0, fk1, idx, idx + HALF, o0, o1);
    unsigned bits = (flat < HALF) ? o0 : o1;
    float f = __uint_as_float((bits >> 9) | 0x3F800000u) - 1.0f;   // [0,1)
    const float LO = __uint_as_float(0xBF7FFFFFu);                  // -1 + 2^-24
    float u = fmaxf(LO, fmaf(f, 2.0f, LO));                         // maxval-minval == 2.0f exactly
    return 1.41421356237f * erfinv_xla(u);
}

// ---------------------------------------------------------------- weight transpose+bf16 prep

__global__ __launch_bounds__(256) void prep_wt_kernel(
    const float* __restrict__ W1, const float* __restrict__ W2,
    const float* __restrict__ W3, const float* __restrict__ W4,
    unsigned short* __restrict__ T1, unsigned short* __restrict__ T2,
    unsigned short* __restrict__ T3, unsigned short* __restrict__ T4)
{
    __shared__ float tile[64][65];
    int b = blockIdx.x;
    const float* W; unsigned short* T; int K, N, kt, nt;
    if (b < 64)       { W = W1; T = T1; K = 512; N = 512; kt = b >> 3; nt = b & 7; }
    else if (b < 96)  { b -= 64;  W = W2; T = T2; K = 512; N = 256; kt = b >> 2; nt = b & 3; }
    else if (b < 128) { b -= 96;  W = W3; T = T3; K = 512; N = 256; kt = b >> 2; nt = b & 3; }
    else              { b -= 128; W = W4; T = T4; K = 256; N = 128; kt = b >> 1; nt = b & 1; }
    const int k0 = kt * 64, n0 = nt * 64;
    const int t = threadIdx.x;

#pragma unroll
    for (int i = 0; i < 4; ++i) {
        int r = (t >> 4) + i * 16;
        int c = (t & 15) * 4;
        float4 v = *reinterpret_cast<const float4*>(&W[(k0 + r) * N + n0 + c]);
        tile[r][c] = v.x; tile[r][c + 1] = v.y; tile[r][c + 2] = v.z; tile[r][c + 3] = v.w;
    }
    __syncthreads();
#pragma unroll
    for (int i = 0; i < 4; ++i) {
        int nn = (t >> 4) + i * 16;
        int kc = (t & 15) * 4;
        ushort4 o;
        o.x = f2bf_rne(tile[kc + 0][nn]);
        o.y = f2bf_rne(tile[kc + 1][nn]);
        o.z = f2bf_rne(tile[kc + 2][nn]);
        o.w = f2bf_rne(tile[kc + 3][nn]);
        *reinterpret_cast<ushort4*>(&T[(n0 + nn) * K + k0 + kc]) = o;
    }
}

// ---------------------------------------------------------------- MFMA GEMM (bf16 inputs, f32 acc)

template <int ACT, int KF, bool EMB>
__global__ __launch_bounds__(256) void gemm_mfma_kernel(
    const float* __restrict__ A,
    const unsigned short* __restrict__ Wt,
    const float* __restrict__ bias,
    float* __restrict__ C, int N)
{
    constexpr int STR = KF + 8;
    __shared__ __align__(16) unsigned short A_s[64 * STR];
    __shared__ __align__(16) unsigned short B_s[64 * STR];
    const int tid = threadIdx.x;
    const int m_base = blockIdx.y * 64;
    const int n_base = blockIdx.x * 64;

    {
        constexpr int ITERS = 64 * KF / 2048;
#pragma unroll
        for (int c = 0; c < ITERS; ++c) {
            const int f = c * 2048 + tid * 8;
            const int row = f / KF, k = f % KF;
            float4 a0, a1;
            if (EMB) {
                const int kk = k & 255;
                a0 = *reinterpret_cast<const float4*>(&A[(m_base + row) * 256 + kk]);
                a1 = *reinterpret_cast<const float4*>(&A[(m_base + row) * 256 + kk + 4]);
                if (k < 256) {
                    a0.x = __cosf(a0.x); a0.y = __cosf(a0.y); a0.z = __cosf(a0.z); a0.w = __cosf(a0.w);
                    a1.x = __cosf(a1.x); a1.y = __cosf(a1.y); a1.z = __cosf(a1.z); a1.w = __cosf(a1.w);
                } else {
                    a0.x = __sinf(a0.x); a0.y = __sinf(a0.y); a0.z = __sinf(a0.z); a0.w = __sinf(a0.w);
                    a1.x = __sinf(a1.x); a1.y = __sinf(a1.y); a1.z = __sinf(a1.z); a1.w = __sinf(a1.w);
                }
            } else {
                a0 = *reinterpret_cast<const float4*>(&A[(m_base + row) * KF + k]);
                a1 = *reinterpret_cast<const float4*>(&A[(m_base + row) * KF + k + 4]);
            }
            short8 v;
            v[0] = (short)f2bf_rne(a0.x); v[1] = (short)f2bf_rne(a0.y);
            v[2] = (short)f2bf_rne(a0.z); v[3] = (short)f2bf_rne(a0.w);
            v[4] = (short)f2bf_rne(a1.x); v[5] = (short)f2bf_rne(a1.y);
            v[6] = (short)f2bf_rne(a1.z); v[7] = (short)f2bf_rne(a1.w);
            *reinterpret_cast<short8*>(&A_s[row * STR + k]) = v;
        }
    }
    {
        constexpr int ITERS = 64 * KF / 2048;
#pragma unroll
        for (int c = 0; c < ITERS; ++c) {
            const int f = c * 2048 + tid * 8;
            const int n = f / KF, k = f % KF;
            short8 v = *reinterpret_cast<const short8*>(&Wt[(n_base + n) * KF + k]);
            *reinterpret_cast<short8*>(&B_s[n * STR + k]) = v;
        }
    }
    __syncthreads();

    const int l = tid & 63, w = tid >> 6;
    const int lo = l & 15, hi = l >> 4;

    f32x4 acc0 = {0.f, 0.f, 0.f, 0.f};
    f32x4 acc1 = {0.f, 0.f, 0.f, 0.f};
    f32x4 acc2 = {0.f, 0.f, 0.f, 0.f};
    f32x4 acc3 = {0.f, 0.f, 0.f, 0.f};
#pragma unroll
    for (int kc = 0; kc < KF / 32; ++kc) {
        short8 af = *reinterpret_cast<const short8*>(&A_s[(w * 16 + lo) * STR + kc * 32 + hi * 8]);
        short8 b0 = *reinterpret_cast<const short8*>(&B_s[(0 * 16 + lo) * STR + kc * 32 + hi * 8]);
        short8 b1 = *reinterpret_cast<const short8*>(&B_s[(1 * 16 + lo) * STR + kc * 32 + hi * 8]);
        short8 b2 = *reinterpret_cast<const short8*>(&B_s[(2 * 16 + lo) * STR + kc * 32 + hi * 8]);
        short8 b3 = *reinterpret_cast<const short8*>(&B_s[(3 * 16 + lo) * STR + kc * 32 + hi * 8]);
        acc0 = __builtin_amdgcn_mfma_f32_16x16x32_bf16(af, b0, acc0, 0, 0, 0);
        acc1 = __builtin_amdgcn_mfma_f32_16x16x32_bf16(af, b1, acc1, 0, 0, 0);
        acc2 = __builtin_amdgcn_mfma_f32_16x16x32_bf16(af, b2, acc2, 0, 0, 0);
        acc3 = __builtin_amdgcn_mfma_f32_16x16x32_bf16(af, b3, acc3, 0, 0, 0);
    }

#pragma unroll
    for (int nf = 0; nf < 4; ++nf) {
        const f32x4 a = (nf == 0) ? acc0 : (nf == 1) ? acc1 : (nf == 2) ? acc2 : acc3;
        const int n = n_base + nf * 16 + lo;
        const float bv = bias[n];
#pragma unroll
        for (int q = 0; q < 4; ++q) {
            const int m = m_base + w * 16 + hi * 4 + q;
            float v = a[q] + bv;
            if (ACT == 1) v = gelu_f(v);
            else if (ACT == 2) v = tanhf(v) * 3.14159274101257324f;
            C[m * N + n] = v;
        }
    }
}

// ---------------------------------------------------------------- Sinkhorn (multiplicative, fp16 E in LDS)

__global__ __launch_bounds__(1024) void sinkhorn_kernel(const float* __restrict__ logits,
                                                        float* __restrict__ P,
                                                        float* __restrict__ scal,
                                                        float* __restrict__ om_add) {
    __shared__ __align__(16) __half Eh[256][260];
    __shared__ float a[256], b[256];
    __shared__ float part[8][256];
    const int t = threadIdx.x;

    if (t < 8) {
        float val = 0.0f;
        if (t == SC_Z) val = 0.1f;
        if (t == SC_KMULT) val = 1.0f;
        scal[t] = val;
    }
    if (t < 256) { om_add[t] = 0.0f; b[t] = 1.0f; }

    {
        const int r = t >> 2, c0 = (t & 3) * 64;
#pragma unroll
        for (int j = 0; j < 64; j += 4) {
            float4 x4 = *reinterpret_cast<const float4*>(&logits[r * 256 + c0 + j]);
            __half2 h01 = __floats2half2_rn(__expf(x4.x), __expf(x4.y));
            __half2 h23 = __floats2half2_rn(__expf(x4.z), __expf(x4.w));
            *reinterpret_cast<__half2*>(&Eh[r][c0 + j])     = h01;
            *reinterpret_cast<__half2*>(&Eh[r][c0 + j + 2]) = h23;
        }
    }
    __syncthreads();

    for (int it = 0; it < 5; ++it) {
        {
            const int i = t & 255, q = t >> 8;
            float s0 = 0.f, s1 = 0.f, s2 = 0.f, s3 = 0.f;
#pragma unroll
            for (int j0 = 0; j0 < 64; j0 += 4) {
                float2 e4 = *reinterpret_cast<const float2*>(&Eh[i][q * 64 + j0]);
                const __half2* hp = reinterpret_cast<const __half2*>(&e4);
                float2 f01 = __half22float2(hp[0]);
                float2 f23 = __half22float2(hp[1]);
                float4 bv = *reinterpret_cast<const float4*>(&b[q * 64 + j0]);
                s0 = fmaf(f01.x, bv.x, s0);
                s1 = fmaf(f01.y, bv.y, s1);
                s2 = fmaf(f23.x, bv.z, s2);
                s3 = fmaf(f23.y, bv.w, s3);
            }
            part[q][i] = (s0 + s1) + (s2 + s3);
        }
        __syncthreads();
        if (t < 256) a[t] = 1.0f / (part[0][t] + part[1][t] + part[2][t] + part[3][t]);
        __syncthreads();
        {
            const int jp = t & 127, seg = t >> 7;
            float s0 = 0.f, s1 = 0.f;
#pragma unroll
            for (int i0 = 0; i0 < 32; i0 += 4) {
                float4 av = *reinterpret_cast<const float4*>(&a[seg * 32 + i0]);
                __half2 e0 = *reinterpret_cast<const __half2*>(&Eh[seg * 32 + i0 + 0][2 * jp]);
                __half2 e1 = *reinterpret_cast<const __half2*>(&Eh[seg * 32 + i0 + 1][2 * jp]);
                __half2 e2 = *reinterpret_cast<const __half2*>(&Eh[seg * 32 + i0 + 2][2 * jp]);
                __half2 e3 = *reinterpret_cast<const __half2*>(&Eh[seg * 32 + i0 + 3][2 * jp]);
                float2 f0 = __half22float2(e0), f1 = __half22float2(e1);
                float2 f2 = __half22float2(e2), f3 = __half22float2(e3);
                s0 = fmaf(f0.x, av.x, s0); s1 = fmaf(f0.y, av.x, s1);
                s0 = fmaf(f1.x, av.y, s0); s1 = fmaf(f1.y, av.y, s1);
                s0 = fmaf(f2.x, av.z, s0); s1 = fmaf(f2.y, av.z, s1);
                s0 = fmaf(f3.x, av.w, s0); s1 = fmaf(f3.y, av.w, s1);
            }
            part[seg][2 * jp]     = s0;
            part[seg][2 * jp + 1] = s1;
        }
        __syncthreads();
        if (t < 256) {
            float s = ((part[0][t] + part[1][t]) + (part[2][t] + part[3][t]))
                    + ((part[4][t] + part[5][t]) + (part[6][t] + part[7][t]));
            b[t] = 1.0f / s;
        }
        __syncthreads();
    }

    {
        const int r = t >> 2, c0 = (t & 3) * 64;
        const float ar = a[r];
#pragma unroll
        for (int j = 0; j < 64; j += 4) {
            float2 e4 = *reinterpret_cast<const float2*>(&Eh[r][c0 + j]);
            const __half2* hp = reinterpret_cast<const __half2*>(&e4);
            float2 f01 = __half22float2(hp[0]);
            float2 f23 = __half22float2(hp[1]);
            float4 bv = *reinterpret_cast<const float4*>(&b[c0 + j]);
            float4 o;
            o.x = f01.x * ar * bv.x;
            o.y = f01.y * ar * bv.y;
            o.z = f23.x * ar * bv.z;
            o.w = f23.y * ar * bv.w;
            *reinterpret_cast<float4*>(&P[r * 256 + c0 + j]) = o;
        }
    }
}

// ---------------------------------------------------------------- MEGA: all 4 layers, cooperative
// 64 blocks x 512 threads; block owns 16 batch rows for the WHOLE layer loop.
// theta lives in LDS; grid.sync() between kuramoto / sel / finalize phases.

__global__ __launch_bounds__(512) void mega_layers_kernel(
    float* theta,
    const float* Kall,
    const float* omega,
    const float* Kg,
    const float* opstr,
    const float* cf,
    const float* sW1,
    const float* sb1,
    const float* sW2,
    const float* sb2,
    const float* zm_p,
    const float* zd_p,
    float* scal,
    float* om_add,
    float* rpart,
    float* partial,
    const float* P)
{
    cg::grid_group grid = cg::this_grid();

    __shared__ __align__(16) unsigned short s_lds[2][16][264];
    __shared__ __align__(16) unsigned short c_lds[2][16][264];
    __shared__ __align__(16) float th_lds[16][260];
    __shared__ float rp_s[16][128];
    __shared__ float rp_c[16][128];
    __shared__ float red_s[16][32];
    __shared__ float red_c[16][32];
    __shared__ float rloc[16];
    __shared__ float red8[8][64];
    __shared__ float hbar[64];
    __shared__ float lg[6];
    __shared__ float s_z, s_rmean, s_sm;
    __shared__ int s_op;

    const int tid = threadIdx.x;
    const int l  = tid & 63;
    const int w  = tid >> 6;       // wave 0..7
    const int lo = l & 15;
    const int hi = l >> 4;         // 0..3
    const int cb = w * 32;
    const int r0 = blockIdx.x * 16;

    // ---- stage theta (encoder output) into LDS ---------------------------
    {
        const int row = tid >> 5;
        const int c0 = (tid & 31) * 8;
        float4 a = *reinterpret_cast<const float4*>(&theta[(r0 + row) * 256 + c0]);
        float4 b = *reinterpret_cast<const float4*>(&theta[(r0 + row) * 256 + c0 + 4]);
        *reinterpret_cast<float4*>(&th_lds[row][c0])     = a;
        *reinterpret_cast<float4*>(&th_lds[row][c0 + 4]) = b;
    }
    __syncthreads();

    for (int li = 0; li < 4; ++li) {
        // ---- K fragments for this layer (registers, via symmetry) --------
        const float* Kl = Kall + li * 65536;
        short8 kfrag[8][2];
#pragma unroll
        for (int nf = 0; nf < 2; ++nf) {
            const int col = cb + nf * 16 + lo;
            const float* krow = Kl + col * 256;
#pragma unroll
            for (int ks = 0; ks < 8; ++ks) {
                const int kb = ks * 32 + hi * 8;
                float4 k0 = *reinterpret_cast<const float4*>(&krow[kb]);
                float4 k1 = *reinterpret_cast<const float4*>(&krow[kb + 4]);
                short8 f;
                f[0] = (short)f2bf_rne(k0.x); f[1] = (short)f2bf_rne(k0.y);
                f[2] = (short)f2bf_rne(k0.z); f[3] = (short)f2bf_rne(k0.w);
                f[4] = (short)f2bf_rne(k1.x); f[5] = (short)f2bf_rne(k1.y);
                f[6] = (short)f2bf_rne(k1.z); f[7] = (short)f2bf_rne(k1.w);
                kfrag[ks][nf] = f;
            }
        }

        const int op_prev = (li == 0) ? 0 : (int)*(volatile float*)(scal + SC_OP);
        const float kmult = (li == 0) ? 1.0f : *(volatile float*)(scal + SC_KMULT);
        const float opv_p = (li == 0) ? 0.0f : *(volatile float*)(scal + SC_OPSTR);
        const float gk = Kg[li] * (1.0f / 256.0f) * kmult;

        // ---- prologue: apply previous layer's operator --------------------
        float t[2][4];
        if (op_prev == 3) {
            float acc[2][4] = {};
            for (int j = 0; j < 256; ++j) {
                float p0 = P[j * 256 + cb + lo];
                float p1 = P[j * 256 + cb + 16 + lo];
#pragma unroll
                for (int q = 0; q < 4; ++q) {
                    float tv = th_lds[hi * 4 + q][j];
                    acc[0][q] = fmaf(tv, p0, acc[0][q]);
                    acc[1][q] = fmaf(tv, p1, acc[1][q]);
                }
            }
#pragma unroll
            for (int nf = 0; nf < 2; ++nf)
#pragma unroll
                for (int q = 0; q < 4; ++q) t[nf][q] = acc[nf][q];
        } else {
#pragma unroll
            for (int nf = 0; nf < 2; ++nf)
#pragma unroll
                for (int q = 0; q < 4; ++q)
                    t[nf][q] = th_lds[hi * 4 + q][cb + nf * 16 + lo];
            if (op_prev == 4) {
                unsigned fk0, fk1;
                threefry2x32(0u, 42u, 0u, (unsigned)(li - 1), fk0, fk1);
#pragma unroll
                for (int nf = 0; nf < 2; ++nf)
#pragma unroll
                    for (int q = 0; q < 4; ++q) {
                        const int row = hi * 4 + q;
                        const int col = cb + nf * 16 + lo;
                        unsigned flat = (unsigned)((r0 + row) * 256 + col);
                        float nz = jax_normal_elem(fk0, fk1, flat);
                        t[nf][q] += nz * opv_p * rloc[row] * 0.2f;
                    }
            }
        }

        // ---- initial sincos -> buffer 0 -----------------------------------
        float si[2][4], ci[2][4];
        float om[2];
#pragma unroll
        for (int nf = 0; nf < 2; ++nf) {
            const int col = cb + nf * 16 + lo;
            om[nf] = omega[li * 256 + col]
                   + ((li == 0) ? 0.0f : *(volatile float*)(om_add + col));
#pragma unroll
            for (int q = 0; q < 4; ++q) {
                const int row = hi * 4 + q;
                float sv, cv;
                __sincosf(t[nf][q], &sv, &cv);
                si[nf][q] = sv; ci[nf][q] = cv;
                s_lds[0][row][col] = f2bf_rne(sv);
                c_lds[0][row][col] = f2bf_rne(cv);
            }
        }
        __syncthreads();

        // ---- 10 steps, ONE barrier each (double-buffered sin/cos) ---------
        int cur = 0;
        for (int s = 0; s < 10; ++s) {
            f32x4 accS0 = {0.f, 0.f, 0.f, 0.f};
            f32x4 accS1 = {0.f, 0.f, 0.f, 0.f};
            f32x4 accC0 = {0.f, 0.f, 0.f, 0.f};
            f32x4 accC1 = {0.f, 0.f, 0.f, 0.f};
#pragma unroll
            for (int ks = 0; ks < 8; ++ks) {
                short8 aS = *reinterpret_cast<const short8*>(&s_lds[cur][lo][ks * 32 + hi * 8]);
                short8 aC = *reinterpret_cast<const short8*>(&c_lds[cur][lo][ks * 32 + hi * 8]);
                accS0 = __builtin_amdgcn_mfma_f32_16x16x32_bf16(aS, kfrag[ks][0], accS0, 0, 0, 0);
                accS1 = __builtin_amdgcn_mfma_f32_16x16x32_bf16(aS, kfrag[ks][1], accS1, 0, 0, 0);
                accC0 = __builtin_amdgcn_mfma_f32_16x16x32_bf16(aC, kfrag[ks][0], accC0, 0, 0, 0);
                accC1 = __builtin_amdgcn_mfma_f32_16x16x32_bf16(aC, kfrag[ks][1], accC1, 0, 0, 0);
            }
            const int nxt = cur ^ 1;
#pragma unroll
            for (int nf = 0; nf < 2; ++nf) {
#pragma unroll
                for (int q = 0; q < 4; ++q) {
                    float aS = (nf == 0) ? accS0[q] : accS1[q];
                    float aC = (nf == 0) ? accC0[q] : accC1[q];
                    float coup = ci[nf][q] * aS - si[nf][q] * aC;
                    float tn = t[nf][q] + DT_F * (om[nf] + gk * coup);
                    t[nf][q] = tn;
                    float sv, cv;
                    __sincosf(tn, &sv, &cv);
                    si[nf][q] = sv; ci[nf][q] = cv;
                    const int row = hi * 4 + q;
                    const int col = cb + nf * 16 + lo;
                    s_lds[nxt][row][col] = f2bf_rne(sv);
                    c_lds[nxt][row][col] = f2bf_rne(cv);
                }
            }
            __syncthreads();
            cur = nxt;
        }

        // ---- epilogue: wrapped theta -> th_lds, r per row, rpart ----------
#pragma unroll
        for (int q = 0; q < 4; ++q) {
            const int row = hi * 4 + q;
            rp_s[row][w * 16 + lo] = si[0][q] + si[1][q];
            rp_c[row][w * 16 + lo] = ci[0][q] + ci[1][q];
        }
#pragma unroll
        for (int nf = 0; nf < 2; ++nf) {
#pragma unroll
            for (int q = 0; q < 4; ++q) {
                const int row = hi * 4 + q;
                const int col = cb + nf * 16 + lo;
                th_lds[row][col] = atan2f(si[nf][q], ci[nf][q]);
            }
        }
        __syncthreads();
        {
            const int row = tid >> 5;
            const int i = tid & 31;
            float ssum = rp_s[row][i] + rp_s[row][i + 32] + rp_s[row][i + 64] + rp_s[row][i + 96];
            float csum = rp_c[row][i] + rp_c[row][i + 32] + rp_c[row][i + 64] + rp_c[row][i + 96];
            red_s[row][i] = ssum;
            red_c[row][i] = csum;
            __syncthreads();
#pragma unroll
            for (int off = 16; off > 0; off >>= 1) {
                if (i < off) {
                    red_s[row][i] += red_s[row][i + off];
                    red_c[row][i] += red_c[row][i + off];
                }
                __syncthreads();
            }
            if (i == 0) {
                float sm = red_s[row][0] * (1.0f / 256.0f);
                float cm = red_c[row][0] * (1.0f / 256.0f);
                rloc[row] = sqrtf(cm * cm + sm * sm);
            }
            __syncthreads();
            if (tid == 0) {
                float s = 0.0f;
#pragma unroll
                for (int rr = 0; rr < 16; ++rr) s += rloc[rr];
                rpart[blockIdx.x] = s;
            }
        }
        __threadfence();
        grid.sync();

        // ---- z (identical computation in every block) ----------------------
        if (tid < 64) {
            float s = *(volatile float*)(rpart + tid);
#pragma unroll
            for (int off = 32; off > 0; off >>= 1) s += __shfl_down(s, off);
            if (tid == 0) {
                float rmean = s * (1.0f / 1024.0f);
                s_rmean = rmean;
                float zp = *(volatile float*)(scal + SC_Z);
                float dz = (*zm_p) * (rmean - zp) - (*zd_p) * (zp - 0.5f);
                float zn = zp + 0.01f * dz;
                s_z = fminf(fmaxf(zn, 0.0f), 1.0f);
            }
        }
        __syncthreads();

        // ---- sel MLP hidden dots for own 16 rows ---------------------------
        {
            const int h = tid & 63;
            const int g = tid >> 6;          // 0..7 -> rows 2g, 2g+1
            const int rA = g * 2, rB = g * 2 + 1;
            const float z = s_z;
            float a0 = 0.f, a1 = 0.f, b0 = 0.f, b1 = 0.f;
#pragma unroll 4
            for (int k = 0; k < 256; k += 2) {
                float w0 = sW1[k * 64 + h];
                float w1 = sW1[(k + 1) * 64 + h];
                a0 = fmaf(th_lds[rA][k],     w0, a0);
                a1 = fmaf(th_lds[rA][k + 1], w1, a1);
                b0 = fmaf(th_lds[rB][k],     w0, b0);
                b1 = fmaf(th_lds[rB][k + 1], w1, b1);
            }
            const float w256 = sW1[256 * 64 + h];
            const float w257 = sW1[257 * 64 + h];
            const float bb = sb1[h];
            float fullA = a0 + a1 + bb + rloc[rA] * w256 + z * w257;
            float fullB = b0 + b1 + bb + rloc[rB] * w256 + z * w257;
            red8[g][h] = gelu_f(fullA) + gelu_f(fullB);
        }
        __syncthreads();
        if (tid < 64) {
            float s = ((red8[0][tid] + red8[1][tid]) + (red8[2][tid] + red8[3][tid]))
                    + ((red8[4][tid] + red8[5][tid]) + (red8[6][tid] + red8[7][tid]));
            partial[blockIdx.x * 64 + tid] = s;
        }
        __threadfence();
        grid.sync();

        // ---- finalize (block 0): op select, scal, om_add -------------------
        if (blockIdx.x == 0) {
            const int h = tid & 63;
            const int q = tid >> 6;      // 0..7 -> blocks [q*8, q*8+8)
            float s = 0.0f;
#pragma unroll
            for (int bb = q * 8; bb < q * 8 + 8; ++bb)
                s += *(volatile float*)(partial + bb * 64 + h);
            red8[q][h] = s;
            __syncthreads();
            if (tid < 64)
                hbar[tid] = (((red8[0][tid] + red8[1][tid]) + (red8[2][tid] + red8[3][tid]))
                           + ((red8[4][tid] + red8[5][tid]) + (red8[6][tid] + red8[7][tid])))
                          * (1.0f / 1024.0f);
            __syncthreads();
            if (tid < 6) {
                float lv = sb2[tid];
                for (int hh = 0; hh < 64; ++hh) lv = fmaf(hbar[hh], sW2[hh * 6 + tid], lv);
                lg[tid] = lv;
            }
            __syncthreads();
            if (tid == 0) {
                scal[SC_Z] = s_z;
                scal[SC_RMEAN] = s_rmean;
                float best = -1e30f;
                int op = 0;
#pragma unroll
                for (int o = 0; o < 6; ++o) {
                    if (lg[o] > best) { best = lg[o]; op = o; }
                }
                float sm = opstr[op] * s_rmean;
                scal[SC_OP] = (float)op;
                scal[SC_OPSTR] = opstr[op];
                scal[SC_SM] = sm;
                scal[SC_KMULT] = (op == 1) ? (1.0f + sm * 0.5f)
                                : (op == 2) ? (1.0f - sm * 0.3f) : 1.0f;
                s_sm = sm;
                s_op = op;
            }
            __syncthreads();
            if (tid < 256) om_add[tid] = (s_op == 5) ? cf[tid] * s_sm : 0.0f;
        }
        __threadfence();
        grid.sync();
    }

    // ---- final operator (from layer 3) + theta writeback ------------------
    {
        const int op = (int)*(volatile float*)(scal + SC_OP);
        const float opv = *(volatile float*)(scal + SC_OPSTR);
        float t[2][4];
        if (op == 3) {
            float acc[2][4] = {};
            for (int j = 0; j < 256; ++j) {
                float p0 = P[j * 256 + cb + lo];
                float p1 = P[j * 256 + cb + 16 + lo];
#pragma unroll
                for (int q = 0; q < 4; ++q) {
                    float tv = th_lds[hi * 4 + q][j];
                    acc[0][q] = fmaf(tv, p0, acc[0][q]);
                    acc[1][q] = fmaf(tv, p1, acc[1][q]);
                }
            }
#pragma unroll
            for (int nf = 0; nf < 2; ++nf)
#pragma unroll
                for (int q = 0; q < 4; ++q) t[nf][q] = acc[nf][q];
        } else {
#pragma unroll
            for (int nf = 0; nf < 2; ++nf)
#pragma unroll
                for (int q = 0; q < 4; ++q)
                    t[nf][q] = th_lds[hi * 4 + q][cb + nf * 16 + lo];
            if (op == 4) {
                unsigned fk0, fk1;
                threefry2x32(0u, 42u, 0u, 3u, fk0, fk1);
#pragma unroll
                for (int nf = 0; nf < 2; ++nf)
#pragma unroll
                    for (int q = 0; q < 4; ++q) {
                        const int row = hi * 4 + q;
                        const int col = cb + nf * 16 + lo;
                        unsigned flat = (unsigned)((r0 + row) * 256 + col);
                        float nz = jax_normal_elem(fk0, fk1, flat);
                        t[nf][q] += nz * opv * rloc[row] * 0.2f;
                    }
            }
        }
#pragma unroll
        for (int nf = 0; nf < 2; ++nf)
#pragma unroll
            for (int q = 0; q < 4; ++q) {
                const int row = hi * 4 + q;
                const int col = cb + nf * 16 + lo;
                theta[(r0 + row) * 256 + col] = t[nf][q];
            }
    }
}

// ---------------------------------------------------------------- launch

extern "C" void kernel_launch(void* const* d_in, const int* in_sizes, int n_in,
                              void* d_out, int out_size, void* d_ws, size_t ws_size,
                              hipStream_t stream) {
    const float* x     = (const float*)d_in[0];
    const float* eW1   = (const float*)d_in[1];
    const float* eb1   = (const float*)d_in[2];
    const float* eW2   = (const float*)d_in[3];
    const float* eb2   = (const float*)d_in[4];
    const float* K     = (const float*)d_in[5];
    const float* omega = (const float*)d_in[6];
    const float* Kg    = (const float*)d_in[7];
    const float* opstr = (const float*)d_in[8];
    const float* exlog = (const float*)d_in[9];
    const float* cfreq = (const float*)d_in[10];
    const float* sW1   = (const float*)d_in[11];
    const float* sb1   = (const float*)d_in[12];
    const float* sW2   = (const float*)d_in[13];
    const float* sb2   = (const float*)d_in[14];
    const float* dW1   = (const float*)d_in[15];
    const float* db1   = (const float*)d_in[16];
    const float* dW2   = (const float*)d_in[17];
    const float* db2   = (const float*)d_in[18];
    const float* zm    = (const float*)d_in[19];
    const float* zd    = (const float*)d_in[20];
    float* out = (float*)d_out;

    float* ws      = (float*)d_ws;
    float* P       = ws;               // 65536
    float* theta   = P + 65536;        // 262144
    float* h       = theta + 262144;   // 524288 (enc hidden)
    float* dh      = h + 524288;       // 262144 (dec hidden)
    float* rbuf    = dh + 262144;      // 1024 (unused, layout kept)
    float* scal    = rbuf + 1024;      // 8
    float* om_add  = scal + 8;         // 256
    float* partial = om_add + 256;     // 64*64
    float* rpart   = partial + 16384;  // 64
    unsigned short* W1t = (unsigned short*)(rpart + 64);                          // 512*512 bf16
    unsigned short* W2t = (unsigned short*)(rpart + 64 + 131072);                 // 512*256
    unsigned short* W3t = (unsigned short*)(rpart + 64 + 131072 + 65536);         // 512*256
    unsigned short* W4t = (unsigned short*)(rpart + 64 + 131072 + 65536 + 65536); // 256*128

    // weight prep + Sinkhorn (also initializes scal/om_add)
    prep_wt_kernel<<<136, 256, 0, stream>>>(eW1, eW2, dW1, dW2, W1t, W2t, W3t, W4t);
    sinkhorn_kernel<<<1, 1024, 0, stream>>>(exlog, P, scal, om_add);

    // encoder (MFMA bf16)
    gemm_mfma_kernel<1, 512, false><<<dim3(8, 16), 256, 0, stream>>>(x, W1t, eb1, h, 512);
    gemm_mfma_kernel<2, 512, false><<<dim3(4, 16), 256, 0, stream>>>(h, W2t, eb2, theta, 256);

    // all 4 layers in ONE cooperative kernel
    {
        void* args[] = {
            (void*)&theta, (void*)&K, (void*)&omega, (void*)&Kg,
            (void*)&opstr, (void*)&cfreq, (void*)&sW1, (void*)&sb1,
            (void*)&sW2, (void*)&sb2, (void*)&zm, (void*)&zd,
            (void*)&scal, (void*)&om_add, (void*)&rpart, (void*)&partial,
            (void*)&P
        };
        hipLaunchCooperativeKernel(mega_layers_kernel, dim3(64), dim3(512),
                                   args, 0, stream);
    }

    // decoder (emb fused into MFMA GEMM1)
    gemm_mfma_kernel<1, 512, true><<<dim3(4, 16), 256, 0, stream>>>(theta, W3t, db1, dh, 256);
    gemm_mfma_kernel<0, 256, false><<<dim3(2, 16), 256, 0, stream>>>(dh, W4t, db2, out, 128);

    (void)in_sizes; (void)n_in; (void)out_size; (void)ws_size;
}

// Round 14
// 222.151 us; speedup vs baseline: 1.9151x; 1.9151x over previous
//
#include <hip/hip_runtime.h>
#include <hip/hip_fp16.h>
#include <math.h>

#define DT_F 0.1f

typedef __attribute__((ext_vector_type(8))) short short8;
typedef __attribute__((ext_vector_type(4))) float f32x4;

// ---------------------------------------------------------------- helpers

__device__ __forceinline__ float gelu_f(float x) {
    return 0.5f * x * (1.0f + erff(x * 0.7071067811865475f));
}

__device__ __forceinline__ unsigned short f2bf_rne(float f) {
    union { float f; unsigned u; } v; v.f = f;
    unsigned x = v.u;
    unsigned r = x + 0x7fffu + ((x >> 16) & 1u);
    return (unsigned short)(r >> 16);
}

__device__ __forceinline__ unsigned rotl32(unsigned v, int d) {
    return (v << d) | (v >> (32 - d));
}

// JAX threefry2x32, 20 rounds
__device__ __forceinline__ void threefry2x32(unsigned k0, unsigned k1,
                                             unsigned x0, unsigned x1,
                                             unsigned& o0, unsigned& o1) {
    unsigned k2 = k0 ^ k1 ^ 0x1BD11BDAu;
    x0 += k0; x1 += k1;
    const int r0[4] = {13, 15, 26, 6};
    const int r1[4] = {17, 29, 16, 24};
#pragma unroll
    for (int g = 0; g < 5; ++g) {
        const int* R = (g & 1) ? r1 : r0;
#pragma unroll
        for (int q = 0; q < 4; ++q) { x0 += x1; x1 = rotl32(x1, R[q]); x1 ^= x0; }
        unsigned a, b;
        switch (g) {
            case 0:  a = k1; b = k2 + 1u; break;
            case 1:  a = k2; b = k0 + 2u; break;
            case 2:  a = k0; b = k1 + 3u; break;
            case 3:  a = k1; b = k2 + 4u; break;
            default: a = k2; b = k0 + 5u; break;
        }
        x0 += a; x1 += b;
    }
    o0 = x0; o1 = x1;
}

// XLA ErfInv32 (Giles polynomial)
__device__ __forceinline__ float erfinv_xla(float x) {
    float w = -log1pf(-x * x);
    float p;
    if (w < 5.0f) {
        w -= 2.5f;
        p = 2.81022636e-08f;
        p = fmaf(p, w, 3.43273939e-07f);
        p = fmaf(p, w, -3.5233877e-06f);
        p = fmaf(p, w, -4.39150654e-06f);
        p = fmaf(p, w, 0.00021858087f);
        p = fmaf(p, w, -0.00125372503f);
        p = fmaf(p, w, -0.00417768164f);
        p = fmaf(p, w, 0.246640727f);
        p = fmaf(p, w, 1.50140941f);
    } else {
        w = sqrtf(w) - 3.0f;
        p = -0.000200214257f;
        p = fmaf(p, w, 0.000100950558f);
        p = fmaf(p, w, 0.00134934322f);
        p = fmaf(p, w, -0.00367342844f);
        p = fmaf(p, w, 0.00573950773f);
        p = fmaf(p, w, -0.0076224613f);
        p = fmaf(p, w, 0.00943887047f);
        p = fmaf(p, w, 1.00167406f);
        p = fmaf(p, w, 2.83297682f);
    }
    return p * x;
}

// jax.random.normal(fold_in(key(42), li), (1024,256)) element at flat index
__device__ __forceinline__ float jax_normal_elem(unsigned fk0, unsigned fk1, unsigned flat) {
    const unsigned HALF = 131072u;  // 1024*256/2
    unsigned idx = (flat < HALF) ? flat : (flat - HALF);
    unsigned o0, o1;
    threefry2x32(fk0, fk1, idx, idx + HALF, o0, o1);
    unsigned bits = (flat < HALF) ? o0 : o1;
    float f = __uint_as_float((bits >> 9) | 0x3F800000u) - 1.0f;   // [0,1)
    const float LO = __uint_as_float(0xBF7FFFFFu);                  // -1 + 2^-24
    float u = fmaxf(LO, fmaf(f, 2.0f, LO));                         // maxval-minval == 2.0f exactly
    return 1.41421356237f * erfinv_xla(u);
}

// hand-rolled grid barrier: agent-scope counter + thread-0 spin
__device__ __forceinline__ void grid_barrier(unsigned* ctr, unsigned target) {
    __syncthreads();
    if (threadIdx.x == 0) {
        __threadfence();   // release all prior writes to device scope
        __hip_atomic_fetch_add(ctr, 1u, __ATOMIC_ACQ_REL, __HIP_MEMORY_SCOPE_AGENT);
        while (__hip_atomic_load(ctr, __ATOMIC_ACQUIRE, __HIP_MEMORY_SCOPE_AGENT) < target) {
            __builtin_amdgcn_s_sleep(2);
        }
    }
    __syncthreads();
}

__device__ __forceinline__ float agent_load(const float* p) {
    return __hip_atomic_load(p, __ATOMIC_RELAXED, __HIP_MEMORY_SCOPE_AGENT);
}

// ---------------------------------------------------------------- weight transpose+bf16 prep

__global__ __launch_bounds__(256) void prep_wt_kernel(
    const float* __restrict__ W1, const float* __restrict__ W2,
    const float* __restrict__ W3, const float* __restrict__ W4,
    unsigned short* __restrict__ T1, unsigned short* __restrict__ T2,
    unsigned short* __restrict__ T3, unsigned short* __restrict__ T4)
{
    __shared__ float tile[64][65];
    int b = blockIdx.x;
    const float* W; unsigned short* T; int K, N, kt, nt;
    if (b < 64)       { W = W1; T = T1; K = 512; N = 512; kt = b >> 3; nt = b & 7; }
    else if (b < 96)  { b -= 64;  W = W2; T = T2; K = 512; N = 256; kt = b >> 2; nt = b & 3; }
    else if (b < 128) { b -= 96;  W = W3; T = T3; K = 512; N = 256; kt = b >> 2; nt = b & 3; }
    else              { b -= 128; W = W4; T = T4; K = 256; N = 128; kt = b >> 1; nt = b & 1; }
    const int k0 = kt * 64, n0 = nt * 64;
    const int t = threadIdx.x;

#pragma unroll
    for (int i = 0; i < 4; ++i) {
        int r = (t >> 4) + i * 16;
        int c = (t & 15) * 4;
        float4 v = *reinterpret_cast<const float4*>(&W[(k0 + r) * N + n0 + c]);
        tile[r][c] = v.x; tile[r][c + 1] = v.y; tile[r][c + 2] = v.z; tile[r][c + 3] = v.w;
    }
    __syncthreads();
#pragma unroll
    for (int i = 0; i < 4; ++i) {
        int nn = (t >> 4) + i * 16;
        int kc = (t & 15) * 4;
        ushort4 o;
        o.x = f2bf_rne(tile[kc + 0][nn]);
        o.y = f2bf_rne(tile[kc + 1][nn]);
        o.z = f2bf_rne(tile[kc + 2][nn]);
        o.w = f2bf_rne(tile[kc + 3][nn]);
        *reinterpret_cast<ushort4*>(&T[(n0 + nn) * K + k0 + kc]) = o;
    }
}

// ---------------------------------------------------------------- MFMA GEMM (bf16 inputs, f32 acc)

template <int ACT, int KF, bool EMB>
__global__ __launch_bounds__(256) void gemm_mfma_kernel(
    const float* __restrict__ A,
    const unsigned short* __restrict__ Wt,
    const float* __restrict__ bias,
    float* __restrict__ C, int N)
{
    constexpr int STR = KF + 8;
    __shared__ __align__(16) unsigned short A_s[64 * STR];
    __shared__ __align__(16) unsigned short B_s[64 * STR];
    const int tid = threadIdx.x;
    const int m_base = blockIdx.y * 64;
    const int n_base = blockIdx.x * 64;

    {
        constexpr int ITERS = 64 * KF / 2048;
#pragma unroll
        for (int c = 0; c < ITERS; ++c) {
            const int f = c * 2048 + tid * 8;
            const int row = f / KF, k = f % KF;
            float4 a0, a1;
            if (EMB) {
                const int kk = k & 255;
                a0 = *reinterpret_cast<const float4*>(&A[(m_base + row) * 256 + kk]);
                a1 = *reinterpret_cast<const float4*>(&A[(m_base + row) * 256 + kk + 4]);
                if (k < 256) {
                    a0.x = __cosf(a0.x); a0.y = __cosf(a0.y); a0.z = __cosf(a0.z); a0.w = __cosf(a0.w);
                    a1.x = __cosf(a1.x); a1.y = __cosf(a1.y); a1.z = __cosf(a1.z); a1.w = __cosf(a1.w);
                } else {
                    a0.x = __sinf(a0.x); a0.y = __sinf(a0.y); a0.z = __sinf(a0.z); a0.w = __sinf(a0.w);
                    a1.x = __sinf(a1.x); a1.y = __sinf(a1.y); a1.z = __sinf(a1.z); a1.w = __sinf(a1.w);
                }
            } else {
                a0 = *reinterpret_cast<const float4*>(&A[(m_base + row) * KF + k]);
                a1 = *reinterpret_cast<const float4*>(&A[(m_base + row) * KF + k + 4]);
            }
            short8 v;
            v[0] = (short)f2bf_rne(a0.x); v[1] = (short)f2bf_rne(a0.y);
            v[2] = (short)f2bf_rne(a0.z); v[3] = (short)f2bf_rne(a0.w);
            v[4] = (short)f2bf_rne(a1.x); v[5] = (short)f2bf_rne(a1.y);
            v[6] = (short)f2bf_rne(a1.z); v[7] = (short)f2bf_rne(a1.w);
            *reinterpret_cast<short8*>(&A_s[row * STR + k]) = v;
        }
    }
    {
        constexpr int ITERS = 64 * KF / 2048;
#pragma unroll
        for (int c = 0; c < ITERS; ++c) {
            const int f = c * 2048 + tid * 8;
            const int n = f / KF, k = f % KF;
            short8 v = *reinterpret_cast<const short8*>(&Wt[(n_base + n) * KF + k]);
            *reinterpret_cast<short8*>(&B_s[n * STR + k]) = v;
        }
    }
    __syncthreads();

    const int l = tid & 63, w = tid >> 6;
    const int lo = l & 15, hi = l >> 4;

    f32x4 acc0 = {0.f, 0.f, 0.f, 0.f};
    f32x4 acc1 = {0.f, 0.f, 0.f, 0.f};
    f32x4 acc2 = {0.f, 0.f, 0.f, 0.f};
    f32x4 acc3 = {0.f, 0.f, 0.f, 0.f};
#pragma unroll
    for (int kc = 0; kc < KF / 32; ++kc) {
        short8 af = *reinterpret_cast<const short8*>(&A_s[(w * 16 + lo) * STR + kc * 32 + hi * 8]);
        short8 b0 = *reinterpret_cast<const short8*>(&B_s[(0 * 16 + lo) * STR + kc * 32 + hi * 8]);
        short8 b1 = *reinterpret_cast<const short8*>(&B_s[(1 * 16 + lo) * STR + kc * 32 + hi * 8]);
        short8 b2 = *reinterpret_cast<const short8*>(&B_s[(2 * 16 + lo) * STR + kc * 32 + hi * 8]);
        short8 b3 = *reinterpret_cast<const short8*>(&B_s[(3 * 16 + lo) * STR + kc * 32 + hi * 8]);
        acc0 = __builtin_amdgcn_mfma_f32_16x16x32_bf16(af, b0, acc0, 0, 0, 0);
        acc1 = __builtin_amdgcn_mfma_f32_16x16x32_bf16(af, b1, acc1, 0, 0, 0);
        acc2 = __builtin_amdgcn_mfma_f32_16x16x32_bf16(af, b2, acc2, 0, 0, 0);
        acc3 = __builtin_amdgcn_mfma_f32_16x16x32_bf16(af, b3, acc3, 0, 0, 0);
    }

#pragma unroll
    for (int nf = 0; nf < 4; ++nf) {
        const f32x4 a = (nf == 0) ? acc0 : (nf == 1) ? acc1 : (nf == 2) ? acc2 : acc3;
        const int n = n_base + nf * 16 + lo;
        const float bv = bias[n];
#pragma unroll
        for (int q = 0; q < 4; ++q) {
            const int m = m_base + w * 16 + hi * 4 + q;
            float v = a[q] + bv;
            if (ACT == 1) v = gelu_f(v);
            else if (ACT == 2) v = tanhf(v) * 3.14159274101257324f;
            C[m * N + n] = v;
        }
    }
}

// ---------------------------------------------------------------- Sinkhorn (multiplicative, fp16 E in LDS)
// Also zeroes the 8 mega barrier counters.

__global__ __launch_bounds__(1024) void sinkhorn_kernel(const float* __restrict__ logits,
                                                        float* __restrict__ P,
                                                        unsigned* __restrict__ counters) {
    __shared__ __align__(16) __half Eh[256][260];
    __shared__ float a[256], b[256];
    __shared__ float part[8][256];
    const int t = threadIdx.x;

    if (t < 8) counters[t] = 0u;
    if (t < 256) b[t] = 1.0f;

    {
        const int r = t >> 2, c0 = (t & 3) * 64;
#pragma unroll
        for (int j = 0; j < 64; j += 4) {
            float4 x4 = *reinterpret_cast<const float4*>(&logits[r * 256 + c0 + j]);
            __half2 h01 = __floats2half2_rn(__expf(x4.x), __expf(x4.y));
            __half2 h23 = __floats2half2_rn(__expf(x4.z), __expf(x4.w));
            *reinterpret_cast<__half2*>(&Eh[r][c0 + j])     = h01;
            *reinterpret_cast<__half2*>(&Eh[r][c0 + j + 2]) = h23;
        }
    }
    __syncthreads();

    for (int it = 0; it < 5; ++it) {
        {
            const int i = t & 255, q = t >> 8;
            float s0 = 0.f, s1 = 0.f, s2 = 0.f, s3 = 0.f;
#pragma unroll
            for (int j0 = 0; j0 < 64; j0 += 4) {
                float2 e4 = *reinterpret_cast<const float2*>(&Eh[i][q * 64 + j0]);
                const __half2* hp = reinterpret_cast<const __half2*>(&e4);
                float2 f01 = __half22float2(hp[0]);
                float2 f23 = __half22float2(hp[1]);
                float4 bv = *reinterpret_cast<const float4*>(&b[q * 64 + j0]);
                s0 = fmaf(f01.x, bv.x, s0);
                s1 = fmaf(f01.y, bv.y, s1);
                s2 = fmaf(f23.x, bv.z, s2);
                s3 = fmaf(f23.y, bv.w, s3);
            }
            part[q][i] = (s0 + s1) + (s2 + s3);
        }
        __syncthreads();
        if (t < 256) a[t] = 1.0f / (part[0][t] + part[1][t] + part[2][t] + part[3][t]);
        __syncthreads();
        {
            const int jp = t & 127, seg = t >> 7;
            float s0 = 0.f, s1 = 0.f;
#pragma unroll
            for (int i0 = 0; i0 < 32; i0 += 4) {
                float4 av = *reinterpret_cast<const float4*>(&a[seg * 32 + i0]);
                __half2 e0 = *reinterpret_cast<const __half2*>(&Eh[seg * 32 + i0 + 0][2 * jp]);
                __half2 e1 = *reinterpret_cast<const __half2*>(&Eh[seg * 32 + i0 + 1][2 * jp]);
                __half2 e2 = *reinterpret_cast<const __half2*>(&Eh[seg * 32 + i0 + 2][2 * jp]);
                __half2 e3 = *reinterpret_cast<const __half2*>(&Eh[seg * 32 + i0 + 3][2 * jp]);
                float2 f0 = __half22float2(e0), f1 = __half22float2(e1);
                float2 f2 = __half22float2(e2), f3 = __half22float2(e3);
                s0 = fmaf(f0.x, av.x, s0); s1 = fmaf(f0.y, av.x, s1);
                s0 = fmaf(f1.x, av.y, s0); s1 = fmaf(f1.y, av.y, s1);
                s0 = fmaf(f2.x, av.z, s0); s1 = fmaf(f2.y, av.z, s1);
                s0 = fmaf(f3.x, av.w, s0); s1 = fmaf(f3.y, av.w, s1);
            }
            part[seg][2 * jp]     = s0;
            part[seg][2 * jp + 1] = s1;
        }
        __syncthreads();
        if (t < 256) {
            float s = ((part[0][t] + part[1][t]) + (part[2][t] + part[3][t]))
                    + ((part[4][t] + part[5][t]) + (part[6][t] + part[7][t]));
            b[t] = 1.0f / s;
        }
        __syncthreads();
    }

    {
        const int r = t >> 2, c0 = (t & 3) * 64;
        const float ar = a[r];
#pragma unroll
        for (int j = 0; j < 64; j += 4) {
            float2 e4 = *reinterpret_cast<const float2*>(&Eh[r][c0 + j]);
            const __half2* hp = reinterpret_cast<const __half2*>(&e4);
            float2 f01 = __half22float2(hp[0]);
            float2 f23 = __half22float2(hp[1]);
            float4 bv = *reinterpret_cast<const float4*>(&b[c0 + j]);
            float4 o;
            o.x = f01.x * ar * bv.x;
            o.y = f01.y * ar * bv.y;
            o.z = f23.x * ar * bv.z;
            o.w = f23.y * ar * bv.w;
            *reinterpret_cast<float4*>(&P[r * 256 + c0 + j]) = o;
        }
    }
}

// ---------------------------------------------------------------- MEGA: all 4 layers, hand-rolled barriers
// 64 blocks x 512 threads; block owns 16 batch rows for the whole loop.
// 2 barriers/layer; every block computes z/op/kmult redundantly (identical
// arithmetic -> identical results), so no block-0 broadcast is needed.

__global__ __launch_bounds__(512) void mega_layers_kernel(
    float* __restrict__ theta,
    const float* __restrict__ Kall,
    const float* __restrict__ omega,
    const float* __restrict__ Kg,
    const float* __restrict__ opstr,
    const float* __restrict__ cf,
    const float* __restrict__ sW1,
    const float* __restrict__ sb1,
    const float* __restrict__ sW2,
    const float* __restrict__ sb2,
    const float* __restrict__ zm_p,
    const float* __restrict__ zd_p,
    float* __restrict__ rpart,
    float* __restrict__ partial,
    const float* __restrict__ P,
    unsigned* __restrict__ ctrs)
{
    __shared__ __align__(16) unsigned short s_lds[2][16][264];
    __shared__ __align__(16) unsigned short c_lds[2][16][264];
    __shared__ __align__(16) float th_lds[16][260];
    __shared__ float rp_s[16][128];
    __shared__ float rp_c[16][128];
    __shared__ float red_s[16][32];
    __shared__ float red_c[16][32];
    __shared__ float rloc[16];
    __shared__ float red8[8][64];
    __shared__ float hbar[64];
    __shared__ float lg[6];
    __shared__ float s_rmean;

    const int tid = threadIdx.x;
    const int l  = tid & 63;
    const int w  = tid >> 6;       // wave 0..7
    const int lo = l & 15;
    const int hi = l >> 4;         // 0..3
    const int cb = w * 32;
    const int r0 = blockIdx.x * 16;

    // carried scalar state (identical across all threads/blocks)
    float z_reg = 0.1f;
    int   op_c  = 0;      // previous layer's op
    float opv_c = 0.0f;   // opstr[op]
    float sm_c  = 0.0f;
    float km_c  = 1.0f;

    // ---- stage theta (encoder output) into LDS ---------------------------
    {
        const int row = tid >> 5;
        const int c0 = (tid & 31) * 8;
        float4 a = *reinterpret_cast<const float4*>(&theta[(r0 + row) * 256 + c0]);
        float4 b = *reinterpret_cast<const float4*>(&theta[(r0 + row) * 256 + c0 + 4]);
        *reinterpret_cast<float4*>(&th_lds[row][c0])     = a;
        *reinterpret_cast<float4*>(&th_lds[row][c0 + 4]) = b;
    }
    __syncthreads();

    for (int li = 0; li < 4; ++li) {
        // ---- K fragments for this layer (registers, via symmetry) --------
        const float* Kl = Kall + li * 65536;
        short8 kfrag[8][2];
#pragma unroll
        for (int nf = 0; nf < 2; ++nf) {
            const int col = cb + nf * 16 + lo;
            const float* krow = Kl + col * 256;
#pragma unroll
            for (int ks = 0; ks < 8; ++ks) {
                const int kb = ks * 32 + hi * 8;
                float4 k0 = *reinterpret_cast<const float4*>(&krow[kb]);
                float4 k1 = *reinterpret_cast<const float4*>(&krow[kb + 4]);
                short8 f;
                f[0] = (short)f2bf_rne(k0.x); f[1] = (short)f2bf_rne(k0.y);
                f[2] = (short)f2bf_rne(k0.z); f[3] = (short)f2bf_rne(k0.w);
                f[4] = (short)f2bf_rne(k1.x); f[5] = (short)f2bf_rne(k1.y);
                f[6] = (short)f2bf_rne(k1.z); f[7] = (short)f2bf_rne(k1.w);
                kfrag[ks][nf] = f;
            }
        }

        const float gk = Kg[li] * (1.0f / 256.0f) * km_c;

        // ---- prologue: apply previous layer's operator --------------------
        float t[2][4];
        if (op_c == 3) {
            float acc[2][4] = {};
            for (int j = 0; j < 256; ++j) {
                float p0 = P[j * 256 + cb + lo];
                float p1 = P[j * 256 + cb + 16 + lo];
#pragma unroll
                for (int q = 0; q < 4; ++q) {
                    float tv = th_lds[hi * 4 + q][j];
                    acc[0][q] = fmaf(tv, p0, acc[0][q]);
                    acc[1][q] = fmaf(tv, p1, acc[1][q]);
                }
            }
#pragma unroll
            for (int nf = 0; nf < 2; ++nf)
#pragma unroll
                for (int q = 0; q < 4; ++q) t[nf][q] = acc[nf][q];
        } else {
#pragma unroll
            for (int nf = 0; nf < 2; ++nf)
#pragma unroll
                for (int q = 0; q < 4; ++q)
                    t[nf][q] = th_lds[hi * 4 + q][cb + nf * 16 + lo];
            if (op_c == 4) {
                unsigned fk0, fk1;
                threefry2x32(0u, 42u, 0u, (unsigned)(li - 1), fk0, fk1);
#pragma unroll
                for (int nf = 0; nf < 2; ++nf)
#pragma unroll
                    for (int q = 0; q < 4; ++q) {
                        const int row = hi * 4 + q;
                        const int col = cb + nf * 16 + lo;
                        unsigned flat = (unsigned)((r0 + row) * 256 + col);
                        float nz = jax_normal_elem(fk0, fk1, flat);
                        t[nf][q] += nz * opv_c * rloc[row] * 0.2f;
                    }
            }
        }

        // ---- initial sincos -> buffer 0 -----------------------------------
        float si[2][4], ci[2][4];
        float om[2];
#pragma unroll
        for (int nf = 0; nf < 2; ++nf) {
            const int col = cb + nf * 16 + lo;
            om[nf] = omega[li * 256 + col] + ((op_c == 5) ? cf[col] * sm_c : 0.0f);
#pragma unroll
            for (int q = 0; q < 4; ++q) {
                const int row = hi * 4 + q;
                float sv, cv;
                __sincosf(t[nf][q], &sv, &cv);
                si[nf][q] = sv; ci[nf][q] = cv;
                s_lds[0][row][col] = f2bf_rne(sv);
                c_lds[0][row][col] = f2bf_rne(cv);
            }
        }
        __syncthreads();

        // ---- 10 steps, ONE block barrier each ------------------------------
        int cur = 0;
        for (int s = 0; s < 10; ++s) {
            f32x4 accS0 = {0.f, 0.f, 0.f, 0.f};
            f32x4 accS1 = {0.f, 0.f, 0.f, 0.f};
            f32x4 accC0 = {0.f, 0.f, 0.f, 0.f};
            f32x4 accC1 = {0.f, 0.f, 0.f, 0.f};
#pragma unroll
            for (int ks = 0; ks < 8; ++ks) {
                short8 aS = *reinterpret_cast<const short8*>(&s_lds[cur][lo][ks * 32 + hi * 8]);
                short8 aC = *reinterpret_cast<const short8*>(&c_lds[cur][lo][ks * 32 + hi * 8]);
                accS0 = __builtin_amdgcn_mfma_f32_16x16x32_bf16(aS, kfrag[ks][0], accS0, 0, 0, 0);
                accS1 = __builtin_amdgcn_mfma_f32_16x16x32_bf16(aS, kfrag[ks][1], accS1, 0, 0, 0);
                accC0 = __builtin_amdgcn_mfma_f32_16x16x32_bf16(aC, kfrag[ks][0], accC0, 0, 0, 0);
                accC1 = __builtin_amdgcn_mfma_f32_16x16x32_bf16(aC, kfrag[ks][1], accC1, 0, 0, 0);
            }
            const int nxt = cur ^ 1;
#pragma unroll
            for (int nf = 0; nf < 2; ++nf) {
#pragma unroll
                for (int q = 0; q < 4; ++q) {
                    float aS = (nf == 0) ? accS0[q] : accS1[q];
                    float aC = (nf == 0) ? accC0[q] : accC1[q];
                    float coup = ci[nf][q] * aS - si[nf][q] * aC;
                    float tn = t[nf][q] + DT_F * (om[nf] + gk * coup);
                    t[nf][q] = tn;
                    float sv, cv;
                    __sincosf(tn, &sv, &cv);
                    si[nf][q] = sv; ci[nf][q] = cv;
                    const int row = hi * 4 + q;
                    const int col = cb + nf * 16 + lo;
                    s_lds[nxt][row][col] = f2bf_rne(sv);
                    c_lds[nxt][row][col] = f2bf_rne(cv);
                }
            }
            __syncthreads();
            cur = nxt;
        }

        // ---- epilogue: wrapped theta -> th_lds, r per row, rpart ----------
#pragma unroll
        for (int q = 0; q < 4; ++q) {
            const int row = hi * 4 + q;
            rp_s[row][w * 16 + lo] = si[0][q] + si[1][q];
            rp_c[row][w * 16 + lo] = ci[0][q] + ci[1][q];
        }
#pragma unroll
        for (int nf = 0; nf < 2; ++nf) {
#pragma unroll
            for (int q = 0; q < 4; ++q) {
                const int row = hi * 4 + q;
                const int col = cb + nf * 16 + lo;
                th_lds[row][col] = atan2f(si[nf][q], ci[nf][q]);
            }
        }
        __syncthreads();
        {
            const int row = tid >> 5;
            const int i = tid & 31;
            float ssum = rp_s[row][i] + rp_s[row][i + 32] + rp_s[row][i + 64] + rp_s[row][i + 96];
            float csum = rp_c[row][i] + rp_c[row][i + 32] + rp_c[row][i + 64] + rp_c[row][i + 96];
            red_s[row][i] = ssum;
            red_c[row][i] = csum;
            __syncthreads();
#pragma unroll
            for (int off = 16; off > 0; off >>= 1) {
                if (i < off) {
                    red_s[row][i] += red_s[row][i + off];
                    red_c[row][i] += red_c[row][i + off];
                }
                __syncthreads();
            }
            if (i == 0) {
                float sm = red_s[row][0] * (1.0f / 256.0f);
                float cm = red_c[row][0] * (1.0f / 256.0f);
                rloc[row] = sqrtf(cm * cm + sm * sm);
            }
            __syncthreads();
            if (tid == 0) {
                float s = 0.0f;
#pragma unroll
                for (int rr = 0; rr < 16; ++rr) s += rloc[rr];
                rpart[blockIdx.x] = s;
            }
        }
        grid_barrier(ctrs + li * 2, 64u);

        // ---- z (every block, identical arithmetic) -------------------------
        if (tid < 64) {
            float s = agent_load(rpart + tid);
#pragma unroll
            for (int off = 32; off > 0; off >>= 1) s += __shfl_down(s, off);
            if (tid == 0) s_rmean = s * (1.0f / 1024.0f);
        }
        __syncthreads();
        const float rmean = s_rmean;
        {
            float dz = (*zm_p) * (rmean - z_reg) - (*zd_p) * (z_reg - 0.5f);
            z_reg = fminf(fmaxf(z_reg + 0.01f * dz, 0.0f), 1.0f);
        }

        // ---- sel MLP hidden dots for own 16 rows ---------------------------
        {
            const int h = tid & 63;
            const int g = tid >> 6;          // 0..7 -> rows 2g, 2g+1
            const int rA = g * 2, rB = g * 2 + 1;
            float a0 = 0.f, a1 = 0.f, b0 = 0.f, b1 = 0.f;
#pragma unroll 4
            for (int k = 0; k < 256; k += 2) {
                float w0 = sW1[k * 64 + h];
                float w1 = sW1[(k + 1) * 64 + h];
                a0 = fmaf(th_lds[rA][k],     w0, a0);
                a1 = fmaf(th_lds[rA][k + 1], w1, a1);
                b0 = fmaf(th_lds[rB][k],     w0, b0);
                b1 = fmaf(th_lds[rB][k + 1], w1, b1);
            }
            const float w256 = sW1[256 * 64 + h];
            const float w257 = sW1[257 * 64 + h];
            const float bb = sb1[h];
            float fullA = a0 + a1 + bb + rloc[rA] * w256 + z_reg * w257;
            float fullB = b0 + b1 + bb + rloc[rB] * w256 + z_reg * w257;
            red8[g][h] = gelu_f(fullA) + gelu_f(fullB);
        }
        __syncthreads();
        if (tid < 64) {
            float s = ((red8[0][tid] + red8[1][tid]) + (red8[2][tid] + red8[3][tid]))
                    + ((red8[4][tid] + red8[5][tid]) + (red8[6][tid] + red8[7][tid]));
            partial[blockIdx.x * 64 + tid] = s;
        }
        grid_barrier(ctrs + li * 2 + 1, 64u);

        // ---- finalize (every block, identical arithmetic) ------------------
        {
            const int h = tid & 63;
            const int q = tid >> 6;      // 0..7 -> blocks [q*8, q*8+8)
            float s = 0.0f;
#pragma unroll
            for (int bb = q * 8; bb < q * 8 + 8; ++bb)
                s += agent_load(partial + bb * 64 + h);
            red8[q][h] = s;
        }
        __syncthreads();
        if (tid < 64)
            hbar[tid] = (((red8[0][tid] + red8[1][tid]) + (red8[2][tid] + red8[3][tid]))
                       + ((red8[4][tid] + red8[5][tid]) + (red8[6][tid] + red8[7][tid])))
                      * (1.0f / 1024.0f);
        __syncthreads();
        if (tid < 6) {
            float lv = sb2[tid];
            for (int hh = 0; hh < 64; ++hh) lv = fmaf(hbar[hh], sW2[hh * 6 + tid], lv);
            lg[tid] = lv;
        }
        __syncthreads();
        {
            float best = -1e30f;
            int op = 0;
#pragma unroll
            for (int o = 0; o < 6; ++o) {
                if (lg[o] > best) { best = lg[o]; op = o; }
            }
            op_c  = op;
            opv_c = opstr[op];
            sm_c  = opv_c * rmean;
            km_c  = (op == 1) ? (1.0f + sm_c * 0.5f)
                  : (op == 2) ? (1.0f - sm_c * 0.3f) : 1.0f;
        }
        __syncthreads();
    }

    // ---- final operator (from layer 3) + theta writeback ------------------
    {
        float t[2][4];
        if (op_c == 3) {
            float acc[2][4] = {};
            for (int j = 0; j < 256; ++j) {
                float p0 = P[j * 256 + cb + lo];
                float p1 = P[j * 256 + cb + 16 + lo];
#pragma unroll
                for (int q = 0; q < 4; ++q) {
                    float tv = th_lds[hi * 4 + q][j];
                    acc[0][q] = fmaf(tv, p0, acc[0][q]);
                    acc[1][q] = fmaf(tv, p1, acc[1][q]);
                }
            }
#pragma unroll
            for (int nf = 0; nf < 2; ++nf)
#pragma unroll
                for (int q = 0; q < 4; ++q) t[nf][q] = acc[nf][q];
        } else {
#pragma unroll
            for (int nf = 0; nf < 2; ++nf)
#pragma unroll
                for (int q = 0; q < 4; ++q)
                    t[nf][q] = th_lds[hi * 4 + q][cb + nf * 16 + lo];
            if (op_c == 4) {
                unsigned fk0, fk1;
                threefry2x32(0u, 42u, 0u, 3u, fk0, fk1);
#pragma unroll
                for (int nf = 0; nf < 2; ++nf)
#pragma unroll
                    for (int q = 0; q < 4; ++q) {
                        const int row = hi * 4 + q;
                        const int col = cb + nf * 16 + lo;
                        unsigned flat = (unsigned)((r0 + row) * 256 + col);
                        float nz = jax_normal_elem(fk0, fk1, flat);
                        t[nf][q] += nz * opv_c * rloc[row] * 0.2f;
                    }
            }
        }
#pragma unroll
        for (int nf = 0; nf < 2; ++nf)
#pragma unroll
            for (int q = 0; q < 4; ++q) {
                const int row = hi * 4 + q;
                const int col = cb + nf * 16 + lo;
                theta[(r0 + row) * 256 + col] = t[nf][q];
            }
    }
}

// ---------------------------------------------------------------- launch

extern "C" void kernel_launch(void* const* d_in, const int* in_sizes, int n_in,
                              void* d_out, int out_size, void* d_ws, size_t ws_size,
                              hipStream_t stream) {
    const float* x     = (const float*)d_in[0];
    const float* eW1   = (const float*)d_in[1];
    const float* eb1   = (const float*)d_in[2];
    const float* eW2   = (const float*)d_in[3];
    const float* eb2   = (const float*)d_in[4];
    const float* K     = (const float*)d_in[5];
    const float* omega = (const float*)d_in[6];
    const float* Kg    = (const float*)d_in[7];
    const float* opstr = (const float*)d_in[8];
    const float* exlog = (const float*)d_in[9];
    const float* cfreq = (const float*)d_in[10];
    const float* sW1   = (const float*)d_in[11];
    const float* sb1   = (const float*)d_in[12];
    const float* sW2   = (const float*)d_in[13];
    const float* sb2   = (const float*)d_in[14];
    const float* dW1   = (const float*)d_in[15];
    const float* db1   = (const float*)d_in[16];
    const float* dW2   = (const float*)d_in[17];
    const float* db2   = (const float*)d_in[18];
    const float* zm    = (const float*)d_in[19];
    const float* zd    = (const float*)d_in[20];
    float* out = (float*)d_out;

    float* ws      = (float*)d_ws;
    float* P       = ws;               // 65536
    float* theta   = P + 65536;        // 262144
    float* h       = theta + 262144;   // 524288 (enc hidden)
    float* dh      = h + 524288;       // 262144 (dec hidden)
    float* rbuf    = dh + 262144;      // 1024 (unused, layout kept)
    float* scal    = rbuf + 1024;      // 8 (unused, layout kept)
    float* om_add  = scal + 8;         // 256 (unused, layout kept)
    float* partial = om_add + 256;     // 64*64
    float* rpart   = partial + 16384;  // 64
    unsigned short* W1t = (unsigned short*)(rpart + 64);                          // 512*512 bf16
    unsigned short* W2t = (unsigned short*)(rpart + 64 + 131072);                 // 512*256
    unsigned short* W3t = (unsigned short*)(rpart + 64 + 131072 + 65536);         // 512*256
    unsigned short* W4t = (unsigned short*)(rpart + 64 + 131072 + 65536 + 65536); // 256*128
    unsigned* counters  = (unsigned*)(rpart + 64 + 131072 + 65536 + 65536 + 16384); // 8

    // weight prep + Sinkhorn (also zeroes barrier counters)
    prep_wt_kernel<<<136, 256, 0, stream>>>(eW1, eW2, dW1, dW2, W1t, W2t, W3t, W4t);
    sinkhorn_kernel<<<1, 1024, 0, stream>>>(exlog, P, counters);

    // encoder (MFMA bf16)
    gemm_mfma_kernel<1, 512, false><<<dim3(8, 16), 256, 0, stream>>>(x, W1t, eb1, h, 512);
    gemm_mfma_kernel<2, 512, false><<<dim3(4, 16), 256, 0, stream>>>(h, W2t, eb2, theta, 256);

    // all 4 layers in ONE kernel with hand-rolled grid barriers
    mega_layers_kernel<<<64, 512, 0, stream>>>(theta, K, omega, Kg, opstr, cfreq,
                                               sW1, sb1, sW2, sb2, zm, zd,
                                               rpart, partial, P, counters);

    // decoder (emb fused into MFMA GEMM1)
    gemm_mfma_kernel<1, 512, true><<<dim3(4, 16), 256, 0, stream>>>(theta, W3t, db1, dh, 256);
    gemm_mfma_kernel<0, 256, false><<<dim3(2, 16), 256, 0, stream>>>(dh, W4t, db2, out, 128);

    (void)in_sizes; (void)n_in; (void)out_size; (void)ws_size;
}

// Round 15
// 213.868 us; speedup vs baseline: 1.9893x; 1.0387x over previous
//
#include <hip/hip_runtime.h>
#include <hip/hip_fp16.h>
#include <math.h>

#define DT_F 0.1f

typedef __attribute__((ext_vector_type(8))) short short8;
typedef __attribute__((ext_vector_type(4))) float f32x4;

// ---------------------------------------------------------------- helpers

__device__ __forceinline__ float gelu_f(float x) {
    return 0.5f * x * (1.0f + erff(x * 0.7071067811865475f));
}

__device__ __forceinline__ unsigned short f2bf_rne(float f) {
    union { float f; unsigned u; } v; v.f = f;
    unsigned x = v.u;
    unsigned r = x + 0x7fffu + ((x >> 16) & 1u);
    return (unsigned short)(r >> 16);
}

__device__ __forceinline__ unsigned rotl32(unsigned v, int d) {
    return (v << d) | (v >> (32 - d));
}

// JAX threefry2x32, 20 rounds
__device__ __forceinline__ void threefry2x32(unsigned k0, unsigned k1,
                                             unsigned x0, unsigned x1,
                                             unsigned& o0, unsigned& o1) {
    unsigned k2 = k0 ^ k1 ^ 0x1BD11BDAu;
    x0 += k0; x1 += k1;
    const int r0[4] = {13, 15, 26, 6};
    const int r1[4] = {17, 29, 16, 24};
#pragma unroll
    for (int g = 0; g < 5; ++g) {
        const int* R = (g & 1) ? r1 : r0;
#pragma unroll
        for (int q = 0; q < 4; ++q) { x0 += x1; x1 = rotl32(x1, R[q]); x1 ^= x0; }
        unsigned a, b;
        switch (g) {
            case 0:  a = k1; b = k2 + 1u; break;
            case 1:  a = k2; b = k0 + 2u; break;
            case 2:  a = k0; b = k1 + 3u; break;
            case 3:  a = k1; b = k2 + 4u; break;
            default: a = k2; b = k0 + 5u; break;
        }
        x0 += a; x1 += b;
    }
    o0 = x0; o1 = x1;
}

// XLA ErfInv32 (Giles polynomial)
__device__ __forceinline__ float erfinv_xla(float x) {
    float w = -log1pf(-x * x);
    float p;
    if (w < 5.0f) {
        w -= 2.5f;
        p = 2.81022636e-08f;
        p = fmaf(p, w, 3.43273939e-07f);
        p = fmaf(p, w, -3.5233877e-06f);
        p = fmaf(p, w, -4.39150654e-06f);
        p = fmaf(p, w, 0.00021858087f);
        p = fmaf(p, w, -0.00125372503f);
        p = fmaf(p, w, -0.00417768164f);
        p = fmaf(p, w, 0.246640727f);
        p = fmaf(p, w, 1.50140941f);
    } else {
        w = sqrtf(w) - 3.0f;
        p = -0.000200214257f;
        p = fmaf(p, w, 0.000100950558f);
        p = fmaf(p, w, 0.00134934322f);
        p = fmaf(p, w, -0.00367342844f);
        p = fmaf(p, w, 0.00573950773f);
        p = fmaf(p, w, -0.0076224613f);
        p = fmaf(p, w, 0.00943887047f);
        p = fmaf(p, w, 1.00167406f);
        p = fmaf(p, w, 2.83297682f);
    }
    return p * x;
}

// jax.random.normal(fold_in(key(42), li), (1024,256)) element at flat index
__device__ __forceinline__ float jax_normal_elem(unsigned fk0, unsigned fk1, unsigned flat) {
    const unsigned HALF = 131072u;  // 1024*256/2
    unsigned idx = (flat < HALF) ? flat : (flat - HALF);
    unsigned o0, o1;
    threefry2x32(fk0, fk1, idx, idx + HALF, o0, o1);
    unsigned bits = (flat < HALF) ? o0 : o1;
    float f = __uint_as_float((bits >> 9) | 0x3F800000u) - 1.0f;   // [0,1)
    const float LO = __uint_as_float(0xBF7FFFFFu);                  // -1 + 2^-24
    float u = fmaxf(LO, fmaf(f, 2.0f, LO));                         // maxval-minval == 2.0f exactly
    return 1.41421356237f * erfinv_xla(u);
}

// ---- agent-scope pub/sub primitives (uncached, no L2 flush needed) -------

__device__ __forceinline__ void agent_store_f(float* p, float v) {
    __hip_atomic_store(p, v, __ATOMIC_RELAXED, __HIP_MEMORY_SCOPE_AGENT);
}
__device__ __forceinline__ float agent_load_f(const float* p) {
    return __hip_atomic_load(p, __ATOMIC_RELAXED, __HIP_MEMORY_SCOPE_AGENT);
}
__device__ __forceinline__ void publish_tag(unsigned* tag, unsigned gen) {
    __hip_atomic_store(tag, gen, __ATOMIC_RELEASE, __HIP_MEMORY_SCOPE_AGENT);
}
__device__ __forceinline__ void wait_tag(const unsigned* tag, unsigned gen) {
    while (__hip_atomic_load(tag, __ATOMIC_ACQUIRE, __HIP_MEMORY_SCOPE_AGENT) < gen)
        __builtin_amdgcn_s_sleep(1);
}

// ---------------------------------------------------------------- weight transpose+bf16 prep

__global__ __launch_bounds__(256) void prep_wt_kernel(
    const float* __restrict__ W1, const float* __restrict__ W2,
    const float* __restrict__ W3, const float* __restrict__ W4,
    unsigned short* __restrict__ T1, unsigned short* __restrict__ T2,
    unsigned short* __restrict__ T3, unsigned short* __restrict__ T4)
{
    __shared__ float tile[64][65];
    int b = blockIdx.x;
    const float* W; unsigned short* T; int K, N, kt, nt;
    if (b < 64)       { W = W1; T = T1; K = 512; N = 512; kt = b >> 3; nt = b & 7; }
    else if (b < 96)  { b -= 64;  W = W2; T = T2; K = 512; N = 256; kt = b >> 2; nt = b & 3; }
    else if (b < 128) { b -= 96;  W = W3; T = T3; K = 512; N = 256; kt = b >> 2; nt = b & 3; }
    else              { b -= 128; W = W4; T = T4; K = 256; N = 128; kt = b >> 1; nt = b & 1; }
    const int k0 = kt * 64, n0 = nt * 64;
    const int t = threadIdx.x;

#pragma unroll
    for (int i = 0; i < 4; ++i) {
        int r = (t >> 4) + i * 16;
        int c = (t & 15) * 4;
        float4 v = *reinterpret_cast<const float4*>(&W[(k0 + r) * N + n0 + c]);
        tile[r][c] = v.x; tile[r][c + 1] = v.y; tile[r][c + 2] = v.z; tile[r][c + 3] = v.w;
    }
    __syncthreads();
#pragma unroll
    for (int i = 0; i < 4; ++i) {
        int nn = (t >> 4) + i * 16;
        int kc = (t & 15) * 4;
        ushort4 o;
        o.x = f2bf_rne(tile[kc + 0][nn]);
        o.y = f2bf_rne(tile[kc + 1][nn]);
        o.z = f2bf_rne(tile[kc + 2][nn]);
        o.w = f2bf_rne(tile[kc + 3][nn]);
        *reinterpret_cast<ushort4*>(&T[(n0 + nn) * K + k0 + kc]) = o;
    }
}

// ---------------------------------------------------------------- MFMA GEMM (bf16 inputs, f32 acc)

template <int ACT, int KF, bool EMB>
__global__ __launch_bounds__(256) void gemm_mfma_kernel(
    const float* __restrict__ A,
    const unsigned short* __restrict__ Wt,
    const float* __restrict__ bias,
    float* __restrict__ C, int N)
{
    constexpr int STR = KF + 8;
    __shared__ __align__(16) unsigned short A_s[64 * STR];
    __shared__ __align__(16) unsigned short B_s[64 * STR];
    const int tid = threadIdx.x;
    const int m_base = blockIdx.y * 64;
    const int n_base = blockIdx.x * 64;

    {
        constexpr int ITERS = 64 * KF / 2048;
#pragma unroll
        for (int c = 0; c < ITERS; ++c) {
            const int f = c * 2048 + tid * 8;
            const int row = f / KF, k = f % KF;
            float4 a0, a1;
            if (EMB) {
                const int kk = k & 255;
                a0 = *reinterpret_cast<const float4*>(&A[(m_base + row) * 256 + kk]);
                a1 = *reinterpret_cast<const float4*>(&A[(m_base + row) * 256 + kk + 4]);
                if (k < 256) {
                    a0.x = __cosf(a0.x); a0.y = __cosf(a0.y); a0.z = __cosf(a0.z); a0.w = __cosf(a0.w);
                    a1.x = __cosf(a1.x); a1.y = __cosf(a1.y); a1.z = __cosf(a1.z); a1.w = __cosf(a1.w);
                } else {
                    a0.x = __sinf(a0.x); a0.y = __sinf(a0.y); a0.z = __sinf(a0.z); a0.w = __sinf(a0.w);
                    a1.x = __sinf(a1.x); a1.y = __sinf(a1.y); a1.z = __sinf(a1.z); a1.w = __sinf(a1.w);
                }
            } else {
                a0 = *reinterpret_cast<const float4*>(&A[(m_base + row) * KF + k]);
                a1 = *reinterpret_cast<const float4*>(&A[(m_base + row) * KF + k + 4]);
            }
            short8 v;
            v[0] = (short)f2bf_rne(a0.x); v[1] = (short)f2bf_rne(a0.y);
            v[2] = (short)f2bf_rne(a0.z); v[3] = (short)f2bf_rne(a0.w);
            v[4] = (short)f2bf_rne(a1.x); v[5] = (short)f2bf_rne(a1.y);
            v[6] = (short)f2bf_rne(a1.z); v[7] = (short)f2bf_rne(a1.w);
            *reinterpret_cast<short8*>(&A_s[row * STR + k]) = v;
        }
    }
    {
        constexpr int ITERS = 64 * KF / 2048;
#pragma unroll
        for (int c = 0; c < ITERS; ++c) {
            const int f = c * 2048 + tid * 8;
            const int n = f / KF, k = f % KF;
            short8 v = *reinterpret_cast<const short8*>(&Wt[(n_base + n) * KF + k]);
            *reinterpret_cast<short8*>(&B_s[n * STR + k]) = v;
        }
    }
    __syncthreads();

    const int l = tid & 63, w = tid >> 6;
    const int lo = l & 15, hi = l >> 4;

    f32x4 acc0 = {0.f, 0.f, 0.f, 0.f};
    f32x4 acc1 = {0.f, 0.f, 0.f, 0.f};
    f32x4 acc2 = {0.f, 0.f, 0.f, 0.f};
    f32x4 acc3 = {0.f, 0.f, 0.f, 0.f};
#pragma unroll
    for (int kc = 0; kc < KF / 32; ++kc) {
        short8 af = *reinterpret_cast<const short8*>(&A_s[(w * 16 + lo) * STR + kc * 32 + hi * 8]);
        short8 b0 = *reinterpret_cast<const short8*>(&B_s[(0 * 16 + lo) * STR + kc * 32 + hi * 8]);
        short8 b1 = *reinterpret_cast<const short8*>(&B_s[(1 * 16 + lo) * STR + kc * 32 + hi * 8]);
        short8 b2 = *reinterpret_cast<const short8*>(&B_s[(2 * 16 + lo) * STR + kc * 32 + hi * 8]);
        short8 b3 = *reinterpret_cast<const short8*>(&B_s[(3 * 16 + lo) * STR + kc * 32 + hi * 8]);
        acc0 = __builtin_amdgcn_mfma_f32_16x16x32_bf16(af, b0, acc0, 0, 0, 0);
        acc1 = __builtin_amdgcn_mfma_f32_16x16x32_bf16(af, b1, acc1, 0, 0, 0);
        acc2 = __builtin_amdgcn_mfma_f32_16x16x32_bf16(af, b2, acc2, 0, 0, 0);
        acc3 = __builtin_amdgcn_mfma_f32_16x16x32_bf16(af, b3, acc3, 0, 0, 0);
    }

#pragma unroll
    for (int nf = 0; nf < 4; ++nf) {
        const f32x4 a = (nf == 0) ? acc0 : (nf == 1) ? acc1 : (nf == 2) ? acc2 : acc3;
        const int n = n_base + nf * 16 + lo;
        const float bv = bias[n];
#pragma unroll
        for (int q = 0; q < 4; ++q) {
            const int m = m_base + w * 16 + hi * 4 + q;
            float v = a[q] + bv;
            if (ACT == 1) v = gelu_f(v);
            else if (ACT == 2) v = tanhf(v) * 3.14159274101257324f;
            C[m * N + n] = v;
        }
    }
}

// ---------------------------------------------------------------- Sinkhorn (multiplicative, fp16 E in LDS)
// Also zeroes the 128 publication tags.

__global__ __launch_bounds__(1024) void sinkhorn_kernel(const float* __restrict__ logits,
                                                        float* __restrict__ P,
                                                        unsigned* __restrict__ tags) {
    __shared__ __align__(16) __half Eh[256][260];
    __shared__ float a[256], b[256];
    __shared__ float part[8][256];
    const int t = threadIdx.x;

    if (t < 128) tags[t] = 0u;
    if (t < 256) b[t] = 1.0f;

    {
        const int r = t >> 2, c0 = (t & 3) * 64;
#pragma unroll
        for (int j = 0; j < 64; j += 4) {
            float4 x4 = *reinterpret_cast<const float4*>(&logits[r * 256 + c0 + j]);
            __half2 h01 = __floats2half2_rn(__expf(x4.x), __expf(x4.y));
            __half2 h23 = __floats2half2_rn(__expf(x4.z), __expf(x4.w));
            *reinterpret_cast<__half2*>(&Eh[r][c0 + j])     = h01;
            *reinterpret_cast<__half2*>(&Eh[r][c0 + j + 2]) = h23;
        }
    }
    __syncthreads();

    for (int it = 0; it < 5; ++it) {
        {
            const int i = t & 255, q = t >> 8;
            float s0 = 0.f, s1 = 0.f, s2 = 0.f, s3 = 0.f;
#pragma unroll
            for (int j0 = 0; j0 < 64; j0 += 4) {
                float2 e4 = *reinterpret_cast<const float2*>(&Eh[i][q * 64 + j0]);
                const __half2* hp = reinterpret_cast<const __half2*>(&e4);
                float2 f01 = __half22float2(hp[0]);
                float2 f23 = __half22float2(hp[1]);
                float4 bv = *reinterpret_cast<const float4*>(&b[q * 64 + j0]);
                s0 = fmaf(f01.x, bv.x, s0);
                s1 = fmaf(f01.y, bv.y, s1);
                s2 = fmaf(f23.x, bv.z, s2);
                s3 = fmaf(f23.y, bv.w, s3);
            }
            part[q][i] = (s0 + s1) + (s2 + s3);
        }
        __syncthreads();
        if (t < 256) a[t] = 1.0f / (part[0][t] + part[1][t] + part[2][t] + part[3][t]);
        __syncthreads();
        {
            const int jp = t & 127, seg = t >> 7;
            float s0 = 0.f, s1 = 0.f;
#pragma unroll
            for (int i0 = 0; i0 < 32; i0 += 4) {
                float4 av = *reinterpret_cast<const float4*>(&a[seg * 32 + i0]);
                __half2 e0 = *reinterpret_cast<const __half2*>(&Eh[seg * 32 + i0 + 0][2 * jp]);
                __half2 e1 = *reinterpret_cast<const __half2*>(&Eh[seg * 32 + i0 + 1][2 * jp]);
                __half2 e2 = *reinterpret_cast<const __half2*>(&Eh[seg * 32 + i0 + 2][2 * jp]);
                __half2 e3 = *reinterpret_cast<const __half2*>(&Eh[seg * 32 + i0 + 3][2 * jp]);
                float2 f0 = __half22float2(e0), f1 = __half22float2(e1);
                float2 f2 = __half22float2(e2), f3 = __half22float2(e3);
                s0 = fmaf(f0.x, av.x, s0); s1 = fmaf(f0.y, av.x, s1);
                s0 = fmaf(f1.x, av.y, s0); s1 = fmaf(f1.y, av.y, s1);
                s0 = fmaf(f2.x, av.z, s0); s1 = fmaf(f2.y, av.z, s1);
                s0 = fmaf(f3.x, av.w, s0); s1 = fmaf(f3.y, av.w, s1);
            }
            part[seg][2 * jp]     = s0;
            part[seg][2 * jp + 1] = s1;
        }
        __syncthreads();
        if (t < 256) {
            float s = ((part[0][t] + part[1][t]) + (part[2][t] + part[3][t]))
                    + ((part[4][t] + part[5][t]) + (part[6][t] + part[7][t]));
            b[t] = 1.0f / s;
        }
        __syncthreads();
    }

    {
        const int r = t >> 2, c0 = (t & 3) * 64;
        const float ar = a[r];
#pragma unroll
        for (int j = 0; j < 64; j += 4) {
            float2 e4 = *reinterpret_cast<const float2*>(&Eh[r][c0 + j]);
            const __half2* hp = reinterpret_cast<const __half2*>(&e4);
            float2 f01 = __half22float2(hp[0]);
            float2 f23 = __half22float2(hp[1]);
            float4 bv = *reinterpret_cast<const float4*>(&b[c0 + j]);
            float4 o;
            o.x = f01.x * ar * bv.x;
            o.y = f01.y * ar * bv.y;
            o.z = f23.x * ar * bv.z;
            o.w = f23.y * ar * bv.w;
            *reinterpret_cast<float4*>(&P[r * 256 + c0 + j]) = o;
        }
    }
}

// ---------------------------------------------------------------- MEGA: all 4 layers, point-to-point sync
// 64 blocks x 512 threads; block owns 16 batch rows for the whole loop.
// Cross-block data via agent-scope atomics (uncached) + per-block generation
// tags; data double-buffered by layer parity (skew < 2 layers, proven).

__global__ __launch_bounds__(512) void mega_layers_kernel(
    float* __restrict__ theta,
    const float* __restrict__ Kall,
    const float* __restrict__ omega,
    const float* __restrict__ Kg,
    const float* __restrict__ opstr,
    const float* __restrict__ cf,
    const float* __restrict__ sW1,
    const float* __restrict__ sb1,
    const float* __restrict__ sW2,
    const float* __restrict__ sb2,
    const float* __restrict__ zm_p,
    const float* __restrict__ zd_p,
    float* __restrict__ rpart2,     // [2][64]
    float* __restrict__ partial2,   // [2][64*64]
    const float* __restrict__ P,
    unsigned* __restrict__ rtag,    // [64]
    unsigned* __restrict__ ptag)    // [64]
{
    __shared__ __align__(16) unsigned short s_lds[2][16][264];
    __shared__ __align__(16) unsigned short c_lds[2][16][264];
    __shared__ __align__(16) float th_lds[16][260];
    __shared__ float rp_s[16][128];
    __shared__ float rp_c[16][128];
    __shared__ float red_s[16][32];
    __shared__ float red_c[16][32];
    __shared__ float rloc[16];
    __shared__ float red8[8][64];
    __shared__ float hbar[64];
    __shared__ float lg[6];
    __shared__ float s_rmean;

    const int tid = threadIdx.x;
    const int l  = tid & 63;
    const int w  = tid >> 6;       // wave 0..7
    const int lo = l & 15;
    const int hi = l >> 4;         // 0..3
    const int cb = w * 32;
    const int r0 = blockIdx.x * 16;

    // carried scalar state (identical across all threads/blocks)
    float z_reg = 0.1f;
    int   op_c  = 0;
    float opv_c = 0.0f;
    float sm_c  = 0.0f;
    float km_c  = 1.0f;

    // ---- stage theta (encoder output) into LDS ---------------------------
    {
        const int row = tid >> 5;
        const int c0 = (tid & 31) * 8;
        float4 a = *reinterpret_cast<const float4*>(&theta[(r0 + row) * 256 + c0]);
        float4 b = *reinterpret_cast<const float4*>(&theta[(r0 + row) * 256 + c0 + 4]);
        *reinterpret_cast<float4*>(&th_lds[row][c0])     = a;
        *reinterpret_cast<float4*>(&th_lds[row][c0 + 4]) = b;
    }
    __syncthreads();

    for (int li = 0; li < 4; ++li) {
        const unsigned gen = (unsigned)(li + 1);
        const int par = li & 1;

        // ---- K fragments for this layer (registers, via symmetry) --------
        const float* Kl = Kall + li * 65536;
        short8 kfrag[8][2];
#pragma unroll
        for (int nf = 0; nf < 2; ++nf) {
            const int col = cb + nf * 16 + lo;
            const float* krow = Kl + col * 256;
#pragma unroll
            for (int ks = 0; ks < 8; ++ks) {
                const int kb = ks * 32 + hi * 8;
                float4 k0 = *reinterpret_cast<const float4*>(&krow[kb]);
                float4 k1 = *reinterpret_cast<const float4*>(&krow[kb + 4]);
                short8 f;
                f[0] = (short)f2bf_rne(k0.x); f[1] = (short)f2bf_rne(k0.y);
                f[2] = (short)f2bf_rne(k0.z); f[3] = (short)f2bf_rne(k0.w);
                f[4] = (short)f2bf_rne(k1.x); f[5] = (short)f2bf_rne(k1.y);
                f[6] = (short)f2bf_rne(k1.z); f[7] = (short)f2bf_rne(k1.w);
                kfrag[ks][nf] = f;
            }
        }

        const float gk = Kg[li] * (1.0f / 256.0f) * km_c;

        // ---- prologue: apply previous layer's operator --------------------
        float t[2][4];
        if (op_c == 3) {
            float acc[2][4] = {};
            for (int j = 0; j < 256; ++j) {
                float p0 = P[j * 256 + cb + lo];
                float p1 = P[j * 256 + cb + 16 + lo];
#pragma unroll
                for (int q = 0; q < 4; ++q) {
                    float tv = th_lds[hi * 4 + q][j];
                    acc[0][q] = fmaf(tv, p0, acc[0][q]);
                    acc[1][q] = fmaf(tv, p1, acc[1][q]);
                }
            }
#pragma unroll
            for (int nf = 0; nf < 2; ++nf)
#pragma unroll
                for (int q = 0; q < 4; ++q) t[nf][q] = acc[nf][q];
        } else {
#pragma unroll
            for (int nf = 0; nf < 2; ++nf)
#pragma unroll
                for (int q = 0; q < 4; ++q)
                    t[nf][q] = th_lds[hi * 4 + q][cb + nf * 16 + lo];
            if (op_c == 4) {
                unsigned fk0, fk1;
                threefry2x32(0u, 42u, 0u, (unsigned)(li - 1), fk0, fk1);
#pragma unroll
                for (int nf = 0; nf < 2; ++nf)
#pragma unroll
                    for (int q = 0; q < 4; ++q) {
                        const int row = hi * 4 + q;
                        const int col = cb + nf * 16 + lo;
                        unsigned flat = (unsigned)((r0 + row) * 256 + col);
                        float nz = jax_normal_elem(fk0, fk1, flat);
                        t[nf][q] += nz * opv_c * rloc[row] * 0.2f;
                    }
            }
        }

        // ---- initial sincos -> buffer 0 -----------------------------------
        float si[2][4], ci[2][4];
        float om[2];
#pragma unroll
        for (int nf = 0; nf < 2; ++nf) {
            const int col = cb + nf * 16 + lo;
            om[nf] = omega[li * 256 + col] + ((op_c == 5) ? cf[col] * sm_c : 0.0f);
#pragma unroll
            for (int q = 0; q < 4; ++q) {
                const int row = hi * 4 + q;
                float sv, cv;
                __sincosf(t[nf][q], &sv, &cv);
                si[nf][q] = sv; ci[nf][q] = cv;
                s_lds[0][row][col] = f2bf_rne(sv);
                c_lds[0][row][col] = f2bf_rne(cv);
            }
        }
        __syncthreads();

        // ---- 10 steps, ONE block barrier each ------------------------------
        int cur = 0;
        for (int s = 0; s < 10; ++s) {
            f32x4 accS0 = {0.f, 0.f, 0.f, 0.f};
            f32x4 accS1 = {0.f, 0.f, 0.f, 0.f};
            f32x4 accC0 = {0.f, 0.f, 0.f, 0.f};
            f32x4 accC1 = {0.f, 0.f, 0.f, 0.f};
#pragma unroll
            for (int ks = 0; ks < 8; ++ks) {
                short8 aS = *reinterpret_cast<const short8*>(&s_lds[cur][lo][ks * 32 + hi * 8]);
                short8 aC = *reinterpret_cast<const short8*>(&c_lds[cur][lo][ks * 32 + hi * 8]);
                accS0 = __builtin_amdgcn_mfma_f32_16x16x32_bf16(aS, kfrag[ks][0], accS0, 0, 0, 0);
                accS1 = __builtin_amdgcn_mfma_f32_16x16x32_bf16(aS, kfrag[ks][1], accS1, 0, 0, 0);
                accC0 = __builtin_amdgcn_mfma_f32_16x16x32_bf16(aC, kfrag[ks][0], accC0, 0, 0, 0);
                accC1 = __builtin_amdgcn_mfma_f32_16x16x32_bf16(aC, kfrag[ks][1], accC1, 0, 0, 0);
            }
            const int nxt = cur ^ 1;
#pragma unroll
            for (int nf = 0; nf < 2; ++nf) {
#pragma unroll
                for (int q = 0; q < 4; ++q) {
                    float aS = (nf == 0) ? accS0[q] : accS1[q];
                    float aC = (nf == 0) ? accC0[q] : accC1[q];
                    float coup = ci[nf][q] * aS - si[nf][q] * aC;
                    float tn = t[nf][q] + DT_F * (om[nf] + gk * coup);
                    t[nf][q] = tn;
                    float sv, cv;
                    __sincosf(tn, &sv, &cv);
                    si[nf][q] = sv; ci[nf][q] = cv;
                    const int row = hi * 4 + q;
                    const int col = cb + nf * 16 + lo;
                    s_lds[nxt][row][col] = f2bf_rne(sv);
                    c_lds[nxt][row][col] = f2bf_rne(cv);
                }
            }
            __syncthreads();
            cur = nxt;
        }

        // ---- epilogue: wrapped theta -> th_lds, r per row, publish rpart ---
#pragma unroll
        for (int q = 0; q < 4; ++q) {
            const int row = hi * 4 + q;
            rp_s[row][w * 16 + lo] = si[0][q] + si[1][q];
            rp_c[row][w * 16 + lo] = ci[0][q] + ci[1][q];
        }
#pragma unroll
        for (int nf = 0; nf < 2; ++nf) {
#pragma unroll
            for (int q = 0; q < 4; ++q) {
                const int row = hi * 4 + q;
                const int col = cb + nf * 16 + lo;
                th_lds[row][col] = atan2f(si[nf][q], ci[nf][q]);
            }
        }
        __syncthreads();
        {
            const int row = tid >> 5;
            const int i = tid & 31;
            float ssum = rp_s[row][i] + rp_s[row][i + 32] + rp_s[row][i + 64] + rp_s[row][i + 96];
            float csum = rp_c[row][i] + rp_c[row][i + 32] + rp_c[row][i + 64] + rp_c[row][i + 96];
            red_s[row][i] = ssum;
            red_c[row][i] = csum;
            __syncthreads();
#pragma unroll
            for (int off = 16; off > 0; off >>= 1) {
                if (i < off) {
                    red_s[row][i] += red_s[row][i + off];
                    red_c[row][i] += red_c[row][i + off];
                }
                __syncthreads();
            }
            if (i == 0) {
                float sm = red_s[row][0] * (1.0f / 256.0f);
                float cm = red_c[row][0] * (1.0f / 256.0f);
                rloc[row] = sqrtf(cm * cm + sm * sm);
            }
            __syncthreads();
            if (tid == 0) {
                float s = 0.0f;
#pragma unroll
                for (int rr = 0; rr < 16; ++rr) s += rloc[rr];
                agent_store_f(rpart2 + par * 64 + blockIdx.x, s);
                publish_tag(rtag + blockIdx.x, gen);
            }
        }

        // ---- z (every block, identical arithmetic) -------------------------
        if (tid < 64) {
            wait_tag(rtag + tid, gen);
            float s = agent_load_f(rpart2 + par * 64 + tid);
#pragma unroll
            for (int off = 32; off > 0; off >>= 1) s += __shfl_down(s, off);
            if (tid == 0) s_rmean = s * (1.0f / 1024.0f);
        }
        __syncthreads();
        const float rmean = s_rmean;
        {
            float dz = (*zm_p) * (rmean - z_reg) - (*zd_p) * (z_reg - 0.5f);
            z_reg = fminf(fmaxf(z_reg + 0.01f * dz, 0.0f), 1.0f);
        }

        // ---- sel MLP hidden dots for own 16 rows ---------------------------
        {
            const int h = tid & 63;
            const int g = tid >> 6;          // 0..7 -> rows 2g, 2g+1
            const int rA = g * 2, rB = g * 2 + 1;
            float a0 = 0.f, a1 = 0.f, b0 = 0.f, b1 = 0.f;
#pragma unroll 4
            for (int k = 0; k < 256; k += 2) {
                float w0 = sW1[k * 64 + h];
                float w1 = sW1[(k + 1) * 64 + h];
                a0 = fmaf(th_lds[rA][k],     w0, a0);
                a1 = fmaf(th_lds[rA][k + 1], w1, a1);
                b0 = fmaf(th_lds[rB][k],     w0, b0);
                b1 = fmaf(th_lds[rB][k + 1], w1, b1);
            }
            const float w256 = sW1[256 * 64 + h];
            const float w257 = sW1[257 * 64 + h];
            const float bb = sb1[h];
            float fullA = a0 + a1 + bb + rloc[rA] * w256 + z_reg * w257;
            float fullB = b0 + b1 + bb + rloc[rB] * w256 + z_reg * w257;
            red8[g][h] = gelu_f(fullA) + gelu_f(fullB);
        }
        __syncthreads();
        if (tid < 64) {
            float s = ((red8[0][tid] + red8[1][tid]) + (red8[2][tid] + red8[3][tid]))
                    + ((red8[4][tid] + red8[5][tid]) + (red8[6][tid] + red8[7][tid]));
            agent_store_f(partial2 + par * 4096 + blockIdx.x * 64 + tid, s);
        }
        __syncthreads();   // drains the agent stores (s_waitcnt before barrier)
        if (tid == 0) publish_tag(ptag + blockIdx.x, gen);

        // ---- finalize (every block, identical arithmetic) ------------------
        if (tid < 64) wait_tag(ptag + tid, gen);
        __syncthreads();
        {
            const int h = tid & 63;
            const int q = tid >> 6;      // 0..7 -> blocks [q*8, q*8+8)
            float s = 0.0f;
#pragma unroll
            for (int bb = q * 8; bb < q * 8 + 8; ++bb)
                s += agent_load_f(partial2 + par * 4096 + bb * 64 + h);
            red8[q][h] = s;
        }
        __syncthreads();
        if (tid < 64)
            hbar[tid] = (((red8[0][tid] + red8[1][tid]) + (red8[2][tid] + red8[3][tid]))
                       + ((red8[4][tid] + red8[5][tid]) + (red8[6][tid] + red8[7][tid])))
                      * (1.0f / 1024.0f);
        __syncthreads();
        if (tid < 6) {
            float lv = sb2[tid];
            for (int hh = 0; hh < 64; ++hh) lv = fmaf(hbar[hh], sW2[hh * 6 + tid], lv);
            lg[tid] = lv;
        }
        __syncthreads();
        {
            float best = -1e30f;
            int op = 0;
#pragma unroll
            for (int o = 0; o < 6; ++o) {
                if (lg[o] > best) { best = lg[o]; op = o; }
            }
            op_c  = op;
            opv_c = opstr[op];
            sm_c  = opv_c * rmean;
            km_c  = (op == 1) ? (1.0f + sm_c * 0.5f)
                  : (op == 2) ? (1.0f - sm_c * 0.3f) : 1.0f;
        }
        __syncthreads();
    }

    // ---- final operator (from layer 3) + theta writeback ------------------
    {
        float t[2][4];
        if (op_c == 3) {
            float acc[2][4] = {};
            for (int j = 0; j < 256; ++j) {
                float p0 = P[j * 256 + cb + lo];
                float p1 = P[j * 256 + cb + 16 + lo];
#pragma unroll
                for (int q = 0; q < 4; ++q) {
                    float tv = th_lds[hi * 4 + q][j];
                    acc[0][q] = fmaf(tv, p0, acc[0][q]);
                    acc[1][q] = fmaf(tv, p1, acc[1][q]);
                }
            }
#pragma unroll
            for (int nf = 0; nf < 2; ++nf)
#pragma unroll
                for (int q = 0; q < 4; ++q) t[nf][q] = acc[nf][q];
        } else {
#pragma unroll
            for (int nf = 0; nf < 2; ++nf)
#pragma unroll
                for (int q = 0; q < 4; ++q)
                    t[nf][q] = th_lds[hi * 4 + q][cb + nf * 16 + lo];
            if (op_c == 4) {
                unsigned fk0, fk1;
                threefry2x32(0u, 42u, 0u, 3u, fk0, fk1);
#pragma unroll
                for (int nf = 0; nf < 2; ++nf)
#pragma unroll
                    for (int q = 0; q < 4; ++q) {
                        const int row = hi * 4 + q;
                        const int col = cb + nf * 16 + lo;
                        unsigned flat = (unsigned)((r0 + row) * 256 + col);
                        float nz = jax_normal_elem(fk0, fk1, flat);
                        t[nf][q] += nz * opv_c * rloc[row] * 0.2f;
                    }
            }
        }
#pragma unroll
        for (int nf = 0; nf < 2; ++nf)
#pragma unroll
            for (int q = 0; q < 4; ++q) {
                const int row = hi * 4 + q;
                const int col = cb + nf * 16 + lo;
                theta[(r0 + row) * 256 + col] = t[nf][q];
            }
    }
}

// ---------------------------------------------------------------- launch

extern "C" void kernel_launch(void* const* d_in, const int* in_sizes, int n_in,
                              void* d_out, int out_size, void* d_ws, size_t ws_size,
                              hipStream_t stream) {
    const float* x     = (const float*)d_in[0];
    const float* eW1   = (const float*)d_in[1];
    const float* eb1   = (const float*)d_in[2];
    const float* eW2   = (const float*)d_in[3];
    const float* eb2   = (const float*)d_in[4];
    const float* K     = (const float*)d_in[5];
    const float* omega = (const float*)d_in[6];
    const float* Kg    = (const float*)d_in[7];
    const float* opstr = (const float*)d_in[8];
    const float* exlog = (const float*)d_in[9];
    const float* cfreq = (const float*)d_in[10];
    const float* sW1   = (const float*)d_in[11];
    const float* sb1   = (const float*)d_in[12];
    const float* sW2   = (const float*)d_in[13];
    const float* sb2   = (const float*)d_in[14];
    const float* dW1   = (const float*)d_in[15];
    const float* db1   = (const float*)d_in[16];
    const float* dW2   = (const float*)d_in[17];
    const float* db2   = (const float*)d_in[18];
    const float* zm    = (const float*)d_in[19];
    const float* zd    = (const float*)d_in[20];
    float* out = (float*)d_out;

    float* ws       = (float*)d_ws;
    float* P        = ws;                 // 65536
    float* theta    = P + 65536;          // 262144
    float* h        = theta + 262144;     // 524288 (enc hidden)
    float* dh       = h + 524288;         // 262144 (dec hidden)
    float* rpart2   = dh + 262144;        // 2*64
    float* partial2 = rpart2 + 128;       // 2*4096
    unsigned short* W1t = (unsigned short*)(partial2 + 8192);   // 512*512 bf16
    unsigned short* W2t = W1t + 262144;                          // 512*256
    unsigned short* W3t = W2t + 131072;                          // 512*256
    unsigned short* W4t = W3t + 131072;                          // 256*128
    unsigned* rtag = (unsigned*)(W4t + 32768);                   // 64
    unsigned* ptag = rtag + 64;                                  // 64

    // weight prep + Sinkhorn (also zeroes publication tags)
    prep_wt_kernel<<<136, 256, 0, stream>>>(eW1, eW2, dW1, dW2, W1t, W2t, W3t, W4t);
    sinkhorn_kernel<<<1, 1024, 0, stream>>>(exlog, P, rtag);

    // encoder (MFMA bf16)
    gemm_mfma_kernel<1, 512, false><<<dim3(8, 16), 256, 0, stream>>>(x, W1t, eb1, h, 512);
    gemm_mfma_kernel<2, 512, false><<<dim3(4, 16), 256, 0, stream>>>(h, W2t, eb2, theta, 256);

    // all 4 layers in ONE kernel with point-to-point agent-atomic sync
    mega_layers_kernel<<<64, 512, 0, stream>>>(theta, K, omega, Kg, opstr, cfreq,
                                               sW1, sb1, sW2, sb2, zm, zd,
                                               rpart2, partial2, P, rtag, ptag);

    // decoder (emb fused into MFMA GEMM1)
    gemm_mfma_kernel<1, 512, true><<<dim3(4, 16), 256, 0, stream>>>(theta, W3t, db1, dh, 256);
    gemm_mfma_kernel<0, 256, false><<<dim3(2, 16), 256, 0, stream>>>(dh, W4t, db2, out, 128);

    (void)in_sizes; (void)n_in; (void)out_size; (void)ws_size;
}

// Round 16
// 213.846 us; speedup vs baseline: 1.9895x; 1.0001x over previous
//
#include <hip/hip_runtime.h>
#include <hip/hip_fp16.h>
#include <math.h>

#define DT_F 0.1f

// scal[] slots
#define SC_Z     0
#define SC_RMEAN 1
#define SC_KMULT 2
#define SC_OP    3
#define SC_OPSTR 4
#define SC_SM    5

typedef __attribute__((ext_vector_type(8))) short short8;
typedef __attribute__((ext_vector_type(4))) float f32x4;

// ---------------------------------------------------------------- helpers

__device__ __forceinline__ float gelu_f(float x) {
    return 0.5f * x * (1.0f + erff(x * 0.7071067811865475f));
}

__device__ __forceinline__ unsigned short f2bf_rne(float f) {
    union { float f; unsigned u; } v; v.f = f;
    unsigned x = v.u;
    unsigned r = x + 0x7fffu + ((x >> 16) & 1u);
    return (unsigned short)(r >> 16);
}

__device__ __forceinline__ unsigned rotl32(unsigned v, int d) {
    return (v << d) | (v >> (32 - d));
}

// JAX threefry2x32, 20 rounds
__device__ __forceinline__ void threefry2x32(unsigned k0, unsigned k1,
                                             unsigned x0, unsigned x1,
                                             unsigned& o0, unsigned& o1) {
    unsigned k2 = k0 ^ k1 ^ 0x1BD11BDAu;
    x0 += k0; x1 += k1;
    const int r0[4] = {13, 15, 26, 6};
    const int r1[4] = {17, 29, 16, 24};
#pragma unroll
    for (int g = 0; g < 5; ++g) {
        const int* R = (g & 1) ? r1 : r0;
#pragma unroll
        for (int q = 0; q < 4; ++q) { x0 += x1; x1 = rotl32(x1, R[q]); x1 ^= x0; }
        unsigned a, b;
        switch (g) {
            case 0:  a = k1; b = k2 + 1u; break;
            case 1:  a = k2; b = k0 + 2u; break;
            case 2:  a = k0; b = k1 + 3u; break;
            case 3:  a = k1; b = k2 + 4u; break;
            default: a = k2; b = k0 + 5u; break;
        }
        x0 += a; x1 += b;
    }
    o0 = x0; o1 = x1;
}

// XLA ErfInv32 (Giles polynomial)
__device__ __forceinline__ float erfinv_xla(float x) {
    float w = -log1pf(-x * x);
    float p;
    if (w < 5.0f) {
        w -= 2.5f;
        p = 2.81022636e-08f;
        p = fmaf(p, w, 3.43273939e-07f);
        p = fmaf(p, w, -3.5233877e-06f);
        p = fmaf(p, w, -4.39150654e-06f);
        p = fmaf(p, w, 0.00021858087f);
        p = fmaf(p, w, -0.00125372503f);
        p = fmaf(p, w, -0.00417768164f);
        p = fmaf(p, w, 0.246640727f);
        p = fmaf(p, w, 1.50140941f);
    } else {
        w = sqrtf(w) - 3.0f;
        p = -0.000200214257f;
        p = fmaf(p, w, 0.000100950558f);
        p = fmaf(p, w, 0.00134934322f);
        p = fmaf(p, w, -0.00367342844f);
        p = fmaf(p, w, 0.00573950773f);
        p = fmaf(p, w, -0.0076224613f);
        p = fmaf(p, w, 0.00943887047f);
        p = fmaf(p, w, 1.00167406f);
        p = fmaf(p, w, 2.83297682f);
    }
    return p * x;
}

// jax.random.normal(fold_in(key(42), li), (1024,256)) element at flat index
__device__ __forceinline__ float jax_normal_elem(unsigned fk0, unsigned fk1, unsigned flat) {
    const unsigned HALF = 131072u;  // 1024*256/2
    unsigned idx = (flat < HALF) ? flat : (flat - HALF);
    unsigned o0, o1;
    threefry2x32(fk0, fk1, idx, idx + HALF, o0, o1);
    unsigned bits = (flat < HALF) ? o0 : o1;
    float f = __uint_as_float((bits >> 9) | 0x3F800000u) - 1.0f;   // [0,1)
    const float LO = __uint_as_float(0xBF7FFFFFu);                  // -1 + 2^-24
    float u = fmaxf(LO, fmaf(f, 2.0f, LO));                         // maxval-minval == 2.0f exactly
    return 1.41421356237f * erfinv_xla(u);
}

// ---------------------------------------------------------------- weight transpose+bf16 prep

__global__ __launch_bounds__(256) void prep_wt_kernel(
    const float* __restrict__ W1, const float* __restrict__ W2,
    const float* __restrict__ W3, const float* __restrict__ W4,
    unsigned short* __restrict__ T1, unsigned short* __restrict__ T2,
    unsigned short* __restrict__ T3, unsigned short* __restrict__ T4)
{
    __shared__ float tile[64][65];
    int b = blockIdx.x;
    const float* W; unsigned short* T; int K, N, kt, nt;
    if (b < 64)       { W = W1; T = T1; K = 512; N = 512; kt = b >> 3; nt = b & 7; }
    else if (b < 96)  { b -= 64;  W = W2; T = T2; K = 512; N = 256; kt = b >> 2; nt = b & 3; }
    else if (b < 128) { b -= 96;  W = W3; T = T3; K = 512; N = 256; kt = b >> 2; nt = b & 3; }
    else              { b -= 128; W = W4; T = T4; K = 256; N = 128; kt = b >> 1; nt = b & 1; }
    const int k0 = kt * 64, n0 = nt * 64;
    const int t = threadIdx.x;

#pragma unroll
    for (int i = 0; i < 4; ++i) {
        int r = (t >> 4) + i * 16;
        int c = (t & 15) * 4;
        float4 v = *reinterpret_cast<const float4*>(&W[(k0 + r) * N + n0 + c]);
        tile[r][c] = v.x; tile[r][c + 1] = v.y; tile[r][c + 2] = v.z; tile[r][c + 3] = v.w;
    }
    __syncthreads();
#pragma unroll
    for (int i = 0; i < 4; ++i) {
        int nn = (t >> 4) + i * 16;
        int kc = (t & 15) * 4;
        ushort4 o;
        o.x = f2bf_rne(tile[kc + 0][nn]);
        o.y = f2bf_rne(tile[kc + 1][nn]);
        o.z = f2bf_rne(tile[kc + 2][nn]);
        o.w = f2bf_rne(tile[kc + 3][nn]);
        *reinterpret_cast<ushort4*>(&T[(n0 + nn) * K + k0 + kc]) = o;
    }
}

// ---------------------------------------------------------------- MFMA GEMM (bf16 inputs, f32 acc)

template <int ACT, int KF, bool EMB>
__global__ __launch_bounds__(256) void gemm_mfma_kernel(
    const float* __restrict__ A,
    const unsigned short* __restrict__ Wt,
    const float* __restrict__ bias,
    float* __restrict__ C, int N)
{
    constexpr int STR = KF + 8;
    __shared__ __align__(16) unsigned short A_s[64 * STR];
    __shared__ __align__(16) unsigned short B_s[64 * STR];
    const int tid = threadIdx.x;
    const int m_base = blockIdx.y * 64;
    const int n_base = blockIdx.x * 64;

    {
        constexpr int ITERS = 64 * KF / 2048;
#pragma unroll
        for (int c = 0; c < ITERS; ++c) {
            const int f = c * 2048 + tid * 8;
            const int row = f / KF, k = f % KF;
            float4 a0, a1;
            if (EMB) {
                const int kk = k & 255;
                a0 = *reinterpret_cast<const float4*>(&A[(m_base + row) * 256 + kk]);
                a1 = *reinterpret_cast<const float4*>(&A[(m_base + row) * 256 + kk + 4]);
                if (k < 256) {
                    a0.x = __cosf(a0.x); a0.y = __cosf(a0.y); a0.z = __cosf(a0.z); a0.w = __cosf(a0.w);
                    a1.x = __cosf(a1.x); a1.y = __cosf(a1.y); a1.z = __cosf(a1.z); a1.w = __cosf(a1.w);
                } else {
                    a0.x = __sinf(a0.x); a0.y = __sinf(a0.y); a0.z = __sinf(a0.z); a0.w = __sinf(a0.w);
                    a1.x = __sinf(a1.x); a1.y = __sinf(a1.y); a1.z = __sinf(a1.z); a1.w = __sinf(a1.w);
                }
            } else {
                a0 = *reinterpret_cast<const float4*>(&A[(m_base + row) * KF + k]);
                a1 = *reinterpret_cast<const float4*>(&A[(m_base + row) * KF + k + 4]);
            }
            short8 v;
            v[0] = (short)f2bf_rne(a0.x); v[1] = (short)f2bf_rne(a0.y);
            v[2] = (short)f2bf_rne(a0.z); v[3] = (short)f2bf_rne(a0.w);
            v[4] = (short)f2bf_rne(a1.x); v[5] = (short)f2bf_rne(a1.y);
            v[6] = (short)f2bf_rne(a1.z); v[7] = (short)f2bf_rne(a1.w);
            *reinterpret_cast<short8*>(&A_s[row * STR + k]) = v;
        }
    }
    {
        constexpr int ITERS = 64 * KF / 2048;
#pragma unroll
        for (int c = 0; c < ITERS; ++c) {
            const int f = c * 2048 + tid * 8;
            const int n = f / KF, k = f % KF;
            short8 v = *reinterpret_cast<const short8*>(&Wt[(n_base + n) * KF + k]);
            *reinterpret_cast<short8*>(&B_s[n * STR + k]) = v;
        }
    }
    __syncthreads();

    const int l = tid & 63, w = tid >> 6;
    const int lo = l & 15, hi = l >> 4;

    f32x4 acc0 = {0.f, 0.f, 0.f, 0.f};
    f32x4 acc1 = {0.f, 0.f, 0.f, 0.f};
    f32x4 acc2 = {0.f, 0.f, 0.f, 0.f};
    f32x4 acc3 = {0.f, 0.f, 0.f, 0.f};
#pragma unroll
    for (int kc = 0; kc < KF / 32; ++kc) {
        short8 af = *reinterpret_cast<const short8*>(&A_s[(w * 16 + lo) * STR + kc * 32 + hi * 8]);
        short8 b0 = *reinterpret_cast<const short8*>(&B_s[(0 * 16 + lo) * STR + kc * 32 + hi * 8]);
        short8 b1 = *reinterpret_cast<const short8*>(&B_s[(1 * 16 + lo) * STR + kc * 32 + hi * 8]);
        short8 b2 = *reinterpret_cast<const short8*>(&B_s[(2 * 16 + lo) * STR + kc * 32 + hi * 8]);
        short8 b3 = *reinterpret_cast<const short8*>(&B_s[(3 * 16 + lo) * STR + kc * 32 + hi * 8]);
        acc0 = __builtin_amdgcn_mfma_f32_16x16x32_bf16(af, b0, acc0, 0, 0, 0);
        acc1 = __builtin_amdgcn_mfma_f32_16x16x32_bf16(af, b1, acc1, 0, 0, 0);
        acc2 = __builtin_amdgcn_mfma_f32_16x16x32_bf16(af, b2, acc2, 0, 0, 0);
        acc3 = __builtin_amdgcn_mfma_f32_16x16x32_bf16(af, b3, acc3, 0, 0, 0);
    }

#pragma unroll
    for (int nf = 0; nf < 4; ++nf) {
        const f32x4 a = (nf == 0) ? acc0 : (nf == 1) ? acc1 : (nf == 2) ? acc2 : acc3;
        const int n = n_base + nf * 16 + lo;
        const float bv = bias[n];
#pragma unroll
        for (int q = 0; q < 4; ++q) {
            const int m = m_base + w * 16 + hi * 4 + q;
            float v = a[q] + bv;
            if (ACT == 1) v = gelu_f(v);
            else if (ACT == 2) v = tanhf(v) * 3.14159274101257324f;
            C[m * N + n] = v;
        }
    }
}

// ---------------------------------------------------------------- Sinkhorn (multiplicative, fp16 E in LDS)

__global__ __launch_bounds__(1024) void sinkhorn_kernel(const float* __restrict__ logits,
                                                        float* __restrict__ P,
                                                        float* __restrict__ scal,
                                                        float* __restrict__ om_add) {
    __shared__ __align__(16) __half Eh[256][260];
    __shared__ float a[256], b[256];
    __shared__ float part[8][256];
    const int t = threadIdx.x;

    if (t < 8) {
        float val = 0.0f;
        if (t == SC_Z) val = 0.1f;
        if (t == SC_KMULT) val = 1.0f;
        scal[t] = val;
    }
    if (t < 256) { om_add[t] = 0.0f; b[t] = 1.0f; }

    {
        const int r = t >> 2, c0 = (t & 3) * 64;
#pragma unroll
        for (int j = 0; j < 64; j += 4) {
            float4 x4 = *reinterpret_cast<const float4*>(&logits[r * 256 + c0 + j]);
            __half2 h01 = __floats2half2_rn(__expf(x4.x), __expf(x4.y));
            __half2 h23 = __floats2half2_rn(__expf(x4.z), __expf(x4.w));
            *reinterpret_cast<__half2*>(&Eh[r][c0 + j])     = h01;
            *reinterpret_cast<__half2*>(&Eh[r][c0 + j + 2]) = h23;
        }
    }
    __syncthreads();

    for (int it = 0; it < 5; ++it) {
        {
            const int i = t & 255, q = t >> 8;
            float s0 = 0.f, s1 = 0.f, s2 = 0.f, s3 = 0.f;
#pragma unroll
            for (int j0 = 0; j0 < 64; j0 += 4) {
                float2 e4 = *reinterpret_cast<const float2*>(&Eh[i][q * 64 + j0]);
                const __half2* hp = reinterpret_cast<const __half2*>(&e4);
                float2 f01 = __half22float2(hp[0]);
                float2 f23 = __half22float2(hp[1]);
                float4 bv = *reinterpret_cast<const float4*>(&b[q * 64 + j0]);
                s0 = fmaf(f01.x, bv.x, s0);
                s1 = fmaf(f01.y, bv.y, s1);
                s2 = fmaf(f23.x, bv.z, s2);
                s3 = fmaf(f23.y, bv.w, s3);
            }
            part[q][i] = (s0 + s1) + (s2 + s3);
        }
        __syncthreads();
        if (t < 256) a[t] = 1.0f / (part[0][t] + part[1][t] + part[2][t] + part[3][t]);
        __syncthreads();
        {
            const int jp = t & 127, seg = t >> 7;
            float s0 = 0.f, s1 = 0.f;
#pragma unroll
            for (int i0 = 0; i0 < 32; i0 += 4) {
                float4 av = *reinterpret_cast<const float4*>(&a[seg * 32 + i0]);
                __half2 e0 = *reinterpret_cast<const __half2*>(&Eh[seg * 32 + i0 + 0][2 * jp]);
                __half2 e1 = *reinterpret_cast<const __half2*>(&Eh[seg * 32 + i0 + 1][2 * jp]);
                __half2 e2 = *reinterpret_cast<const __half2*>(&Eh[seg * 32 + i0 + 2][2 * jp]);
                __half2 e3 = *reinterpret_cast<const __half2*>(&Eh[seg * 32 + i0 + 3][2 * jp]);
                float2 f0 = __half22float2(e0), f1 = __half22float2(e1);
                float2 f2 = __half22float2(e2), f3 = __half22float2(e3);
                s0 = fmaf(f0.x, av.x, s0); s1 = fmaf(f0.y, av.x, s1);
                s0 = fmaf(f1.x, av.y, s0); s1 = fmaf(f1.y, av.y, s1);
                s0 = fmaf(f2.x, av.z, s0); s1 = fmaf(f2.y, av.z, s1);
                s0 = fmaf(f3.x, av.w, s0); s1 = fmaf(f3.y, av.w, s1);
            }
            part[seg][2 * jp]     = s0;
            part[seg][2 * jp + 1] = s1;
        }
        __syncthreads();
        if (t < 256) {
            float s = ((part[0][t] + part[1][t]) + (part[2][t] + part[3][t]))
                    + ((part[4][t] + part[5][t]) + (part[6][t] + part[7][t]));
            b[t] = 1.0f / s;
        }
        __syncthreads();
    }

    {
        const int r = t >> 2, c0 = (t & 3) * 64;
        const float ar = a[r];
#pragma unroll
        for (int j = 0; j < 64; j += 4) {
            float2 e4 = *reinterpret_cast<const float2*>(&Eh[r][c0 + j]);
            const __half2* hp = reinterpret_cast<const __half2*>(&e4);
            float2 f01 = __half22float2(hp[0]);
            float2 f23 = __half22float2(hp[1]);
            float4 bv = *reinterpret_cast<const float4*>(&b[c0 + j]);
            float4 o;
            o.x = f01.x * ar * bv.x;
            o.y = f01.y * ar * bv.y;
            o.z = f23.x * ar * bv.z;
            o.w = f23.y * ar * bv.w;
            *reinterpret_cast<float4*>(&P[r * 256 + c0 + j]) = o;
        }
    }
}

// ---------------------------------------------------------------- Kuramoto layer via MFMA
// 64 blocks x 1024 threads (16 waves, 4/SIMD -> MFMA/VALU co-scheduling);
// wave w owns cols [w*16,+16). Double-buffered sin/cos: ONE barrier per step.

__global__ __launch_bounds__(1024, 4) void kuramoto_mfma_kernel(
    float* __restrict__ theta,
    const float* __restrict__ Kl,
    const float* __restrict__ omega_l,
    const float* __restrict__ Kg_p,
    const float* __restrict__ scal,
    const float* __restrict__ om_add,
    float* __restrict__ r_out,
    float* __restrict__ rpart,
    const float* __restrict__ P,
    int li)
{
    __shared__ __align__(16) unsigned short s_lds[2][16][264];
    __shared__ __align__(16) unsigned short c_lds[2][16][264];
    __shared__ __align__(16) float th_lds[16][260];
    __shared__ float rp_s[16][256];
    __shared__ float rp_c[16][256];
    __shared__ float rloc[16];

    const int tid = threadIdx.x;
    const int l  = tid & 63;
    const int w  = tid >> 6;       // wave 0..15
    const int lo = l & 15;
    const int hi = l >> 4;         // 0..3
    const int col = w * 16 + lo;
    const int r0 = blockIdx.x * 16;

    const float gk = Kg_p[0] * (1.0f / 256.0f) * scal[SC_KMULT];
    const int op_prev = (int)scal[SC_OP];

    // ---- stage theta rows to LDS (coalesced: 1024 thr x float4) ---------
    {
        const int row = tid >> 6;
        const int c0 = (tid & 63) * 4;
        float4 a = *reinterpret_cast<const float4*>(&theta[(r0 + row) * 256 + c0]);
        *reinterpret_cast<float4*>(&th_lds[row][c0]) = a;
    }

    // ---- K fragments (registers, bf16) via symmetry ----------------------
    short8 kfrag[8];
    {
        const float* krow = Kl + col * 256;
#pragma unroll
        for (int ks = 0; ks < 8; ++ks) {
            const int kb = ks * 32 + hi * 8;
            float4 k0 = *reinterpret_cast<const float4*>(&krow[kb]);
            float4 k1 = *reinterpret_cast<const float4*>(&krow[kb + 4]);
            short8 f;
            f[0] = (short)f2bf_rne(k0.x); f[1] = (short)f2bf_rne(k0.y);
            f[2] = (short)f2bf_rne(k0.z); f[3] = (short)f2bf_rne(k0.w);
            f[4] = (short)f2bf_rne(k1.x); f[5] = (short)f2bf_rne(k1.y);
            f[6] = (short)f2bf_rne(k1.z); f[7] = (short)f2bf_rne(k1.w);
            kfrag[ks] = f;
        }
    }
    __syncthreads();

    // ---- apply previous operator -----------------------------------------
    float t[4];
    if (op_prev == 3) {
        float a0 = 0.f, a1 = 0.f, a2 = 0.f, a3 = 0.f;
        for (int j = 0; j < 256; ++j) {
            float pv = P[j * 256 + col];
            a0 = fmaf(th_lds[hi * 4 + 0][j], pv, a0);
            a1 = fmaf(th_lds[hi * 4 + 1][j], pv, a1);
            a2 = fmaf(th_lds[hi * 4 + 2][j], pv, a2);
            a3 = fmaf(th_lds[hi * 4 + 3][j], pv, a3);
        }
        t[0] = a0; t[1] = a1; t[2] = a2; t[3] = a3;
    } else {
#pragma unroll
        for (int q = 0; q < 4; ++q) t[q] = th_lds[hi * 4 + q][col];
        if (op_prev == 4) {
            unsigned fk0, fk1;
            threefry2x32(0u, 42u, 0u, (unsigned)(li - 1), fk0, fk1);
            const float opv = scal[SC_OPSTR];
#pragma unroll
            for (int q = 0; q < 4; ++q) {
                const int row = hi * 4 + q;
                unsigned flat = (unsigned)((r0 + row) * 256 + col);
                float nz = jax_normal_elem(fk0, fk1, flat);
                t[q] += nz * opv * r_out[r0 + row] * 0.2f;
            }
        }
    }

    // ---- initial sincos -> buffer 0 ---------------------------------------
    const float om = omega_l[col] + om_add[col];
    float si[4], ci[4];
#pragma unroll
    for (int q = 0; q < 4; ++q) {
        float sv, cv;
        __sincosf(t[q], &sv, &cv);
        si[q] = sv; ci[q] = cv;
        s_lds[0][hi * 4 + q][col] = f2bf_rne(sv);
        c_lds[0][hi * 4 + q][col] = f2bf_rne(cv);
    }
    __syncthreads();

    // ---- 10 steps, single barrier each ------------------------------------
    int cur = 0;
    for (int s = 0; s < 10; ++s) {
        f32x4 accS = {0.f, 0.f, 0.f, 0.f};
        f32x4 accC = {0.f, 0.f, 0.f, 0.f};
#pragma unroll
        for (int ks = 0; ks < 8; ++ks) {
            short8 aS = *reinterpret_cast<const short8*>(&s_lds[cur][lo][ks * 32 + hi * 8]);
            short8 aC = *reinterpret_cast<const short8*>(&c_lds[cur][lo][ks * 32 + hi * 8]);
            accS = __builtin_amdgcn_mfma_f32_16x16x32_bf16(aS, kfrag[ks], accS, 0, 0, 0);
            accC = __builtin_amdgcn_mfma_f32_16x16x32_bf16(aC, kfrag[ks], accC, 0, 0, 0);
        }
        const int nxt = cur ^ 1;
#pragma unroll
        for (int q = 0; q < 4; ++q) {
            float coup = ci[q] * accS[q] - si[q] * accC[q];
            float tn = t[q] + DT_F * (om + gk * coup);
            t[q] = tn;
            float sv, cv;
            __sincosf(tn, &sv, &cv);
            si[q] = sv; ci[q] = cv;
            s_lds[nxt][hi * 4 + q][col] = f2bf_rne(sv);
            c_lds[nxt][hi * 4 + q][col] = f2bf_rne(cv);
        }
        __syncthreads();
        cur = nxt;
    }

    // ---- order parameter r + theta writeback -------------------------------
#pragma unroll
    for (int q = 0; q < 4; ++q) {
        const int row = hi * 4 + q;
        rp_s[row][col] = si[q];
        rp_c[row][col] = ci[q];
        theta[(r0 + row) * 256 + col] = atan2f(si[q], ci[q]);
    }
    __syncthreads();

    {
        // wave w reduces row w (64 lanes x 4 cols each), pure shuffle
        float s = rp_s[w][l] + rp_s[w][l + 64] + rp_s[w][l + 128] + rp_s[w][l + 192];
        float c = rp_c[w][l] + rp_c[w][l + 64] + rp_c[w][l + 128] + rp_c[w][l + 192];
#pragma unroll
        for (int off = 32; off > 0; off >>= 1) {
            s += __shfl_down(s, off);
            c += __shfl_down(c, off);
        }
        if (l == 0) {
            float sm = s * (1.0f / 256.0f);
            float cm = c * (1.0f / 256.0f);
            float rv = sqrtf(cm * cm + sm * sm);
            r_out[r0 + w] = rv;
            rloc[w] = rv;
        }
        __syncthreads();
        if (tid == 0) {
            float acc = 0.0f;
#pragma unroll
            for (int rr = 0; rr < 16; ++rr) acc += rloc[rr];
            rpart[blockIdx.x] = acc;
        }
    }
}

// ---------------------------------------------------------------- selection MLP (W1 + theta staged in LDS)

__global__ __launch_bounds__(256) void sel_partial_kernel(const float* __restrict__ theta,
                                                          const float* __restrict__ rbuf,
                                                          const float* __restrict__ rpart,
                                                          const float* __restrict__ scal,
                                                          const float* __restrict__ W1,
                                                          const float* __restrict__ b1,
                                                          const float* __restrict__ zm_p,
                                                          const float* __restrict__ zd_p,
                                                          float* __restrict__ partial) {
    __shared__ float Wt[64][261];
    __shared__ float th_s[4][256];
    __shared__ float gl[4][64];
    __shared__ float s_z;
    const int t = threadIdx.x;
    const int h = t & 63;
    const int rr = t >> 6;
    const int blk = blockIdx.x;

    if (t < 64) {
        float s = rpart[t];
#pragma unroll
        for (int off = 32; off > 0; off >>= 1) s += __shfl_down(s, off);
        if (t == 0) {
            float rmean = s * (1.0f / 1024.0f);
            float zp = scal[SC_Z];
            float dz = (*zm_p) * (rmean - zp) - (*zd_p) * (zp - 0.5f);
            float zn = zp + 0.01f * dz;
            s_z = fminf(fmaxf(zn, 0.0f), 1.0f);
        }
    }

    for (int idx = t; idx < 258 * 64; idx += 256)
        Wt[idx & 63][idx >> 6] = W1[idx];

    {
        const int c0 = h * 4;
        float4 v = *reinterpret_cast<const float4*>(&theta[(blk * 4 + rr) * 256 + c0]);
        *reinterpret_cast<float4*>(&th_s[rr][c0]) = v;
    }
    __syncthreads();

    const float z = s_z;
    float d0 = 0.f, d1 = 0.f, d2 = 0.f, d3 = 0.f;
#pragma unroll 4
    for (int k0 = 0; k0 < 256; k0 += 4) {
        float4 tv = *reinterpret_cast<const float4*>(&th_s[rr][k0]);
        d0 = fmaf(tv.x, Wt[h][k0 + 0], d0);
        d1 = fmaf(tv.y, Wt[h][k0 + 1], d1);
        d2 = fmaf(tv.z, Wt[h][k0 + 2], d2);
        d3 = fmaf(tv.w, Wt[h][k0 + 3], d3);
    }
    float full = (d0 + d1) + (d2 + d3) + b1[h]
               + rbuf[blk * 4 + rr] * Wt[h][256] + z * Wt[h][257];
    gl[rr][h] = gelu_f(full);
    __syncthreads();
    if (t < 64) partial[blk * 64 + t] = ((gl[0][t] + gl[1][t]) + gl[2][t]) + gl[3][t];
}

// ---------------------------------------------------------------- finalize: z commit + op select

__global__ __launch_bounds__(256) void op_finalize_kernel(const float* __restrict__ partial,
                                                          const float* __restrict__ W2,
                                                          const float* __restrict__ b2,
                                                          const float* __restrict__ opstr,
                                                          const float* __restrict__ cf,
                                                          const float* __restrict__ rpart,
                                                          const float* __restrict__ zm_p,
                                                          const float* __restrict__ zd_p,
                                                          float* __restrict__ scal,
                                                          float* __restrict__ om_add) {
    __shared__ float red[4][64];
    __shared__ float hbar[64];
    __shared__ float lg[6];
    __shared__ float s_rmean;
    __shared__ float s_sm;
    __shared__ int s_op;
    const int t = threadIdx.x;
    const int h = t & 63;
    const int q = t >> 6;

    if (t < 64) {
        float s = rpart[t];
#pragma unroll
        for (int off = 32; off > 0; off >>= 1) s += __shfl_down(s, off);
        if (t == 0) s_rmean = s * (1.0f / 1024.0f);
    }

    float s = 0.0f;
#pragma unroll 8
    for (int blk = q * 64; blk < q * 64 + 64; ++blk) s += partial[blk * 64 + h];
    red[q][h] = s;
    __syncthreads();
    if (t < 64) hbar[t] = (red[0][t] + red[1][t] + red[2][t] + red[3][t]) * (1.0f / 1024.0f);
    __syncthreads();
    if (t < 6) {
        float l = b2[t];
        for (int hh = 0; hh < 64; ++hh) l = fmaf(hbar[hh], W2[hh * 6 + t], l);
        lg[t] = l;
    }
    __syncthreads();
    if (t == 0) {
        float rmean = s_rmean;
        float zp = scal[SC_Z];
        float dz = (*zm_p) * (rmean - zp) - (*zd_p) * (zp - 0.5f);
        float zn = zp + 0.01f * dz;
        zn = fminf(fmaxf(zn, 0.0f), 1.0f);
        scal[SC_Z] = zn;
        scal[SC_RMEAN] = rmean;

        float best = -1e30f;
        int op = 0;
#pragma unroll
        for (int o = 0; o < 6; ++o) {
            if (lg[o] > best) { best = lg[o]; op = o; }
        }
        float sm = opstr[op] * rmean;
        scal[SC_OP] = (float)op;
        scal[SC_OPSTR] = opstr[op];
        scal[SC_SM] = sm;
        scal[SC_KMULT] = (op == 1) ? (1.0f + sm * 0.5f)
                        : (op == 2) ? (1.0f - sm * 0.3f) : 1.0f;
        s_sm = sm;
        s_op = op;
    }
    __syncthreads();
    om_add[t] = (s_op == 5) ? cf[t] * s_sm : 0.0f;
}

// ---------------------------------------------------------------- standalone apply (last layer only)

__global__ __launch_bounds__(256) void apply_op_kernel(float* __restrict__ theta,
                                                       const float* __restrict__ P,
                                                       const float* __restrict__ r,
                                                       const float* __restrict__ scal,
                                                       int li) {
    __shared__ float th[8][256];
    const int op = (int)scal[SC_OP];
    const int i = threadIdx.x;
    const int b0 = blockIdx.x * 8;

    if (op == 3) {
#pragma unroll
        for (int rr = 0; rr < 8; ++rr) th[rr][i] = theta[(b0 + rr) * 256 + i];
        __syncthreads();
        float acc[8] = {0.f, 0.f, 0.f, 0.f, 0.f, 0.f, 0.f, 0.f};
        for (int j = 0; j < 256; ++j) {
            float pv = P[j * 256 + i];
#pragma unroll
            for (int rr = 0; rr < 8; ++rr) acc[rr] = fmaf(th[rr][j], pv, acc[rr]);
        }
#pragma unroll
        for (int rr = 0; rr < 8; ++rr) theta[(b0 + rr) * 256 + i] = acc[rr];
    } else if (op == 4) {
        unsigned fk0, fk1;
        threefry2x32(0u, 42u, 0u, (unsigned)li, fk0, fk1);
        const float opv = scal[SC_OPSTR];
#pragma unroll
        for (int rr = 0; rr < 8; ++rr) {
            int b = b0 + rr;
            unsigned flat = (unsigned)(b * 256 + i);
            float nz = jax_normal_elem(fk0, fk1, flat);
            float strength = opv * r[b];
            theta[b * 256 + i] += nz * strength * 0.2f;
        }
    }
}

// ---------------------------------------------------------------- launch

extern "C" void kernel_launch(void* const* d_in, const int* in_sizes, int n_in,
                              void* d_out, int out_size, void* d_ws, size_t ws_size,
                              hipStream_t stream) {
    const float* x     = (const float*)d_in[0];
    const float* eW1   = (const float*)d_in[1];
    const float* eb1   = (const float*)d_in[2];
    const float* eW2   = (const float*)d_in[3];
    const float* eb2   = (const float*)d_in[4];
    const float* K     = (const float*)d_in[5];
    const float* omega = (const float*)d_in[6];
    const float* Kg    = (const float*)d_in[7];
    const float* opstr = (const float*)d_in[8];
    const float* exlog = (const float*)d_in[9];
    const float* cfreq = (const float*)d_in[10];
    const float* sW1   = (const float*)d_in[11];
    const float* sb1   = (const float*)d_in[12];
    const float* sW2   = (const float*)d_in[13];
    const float* sb2   = (const float*)d_in[14];
    const float* dW1   = (const float*)d_in[15];
    const float* db1   = (const float*)d_in[16];
    const float* dW2   = (const float*)d_in[17];
    const float* db2   = (const float*)d_in[18];
    const float* zm    = (const float*)d_in[19];
    const float* zd    = (const float*)d_in[20];
    float* out = (float*)d_out;

    float* ws      = (float*)d_ws;
    float* P       = ws;               // 65536
    float* theta   = P + 65536;        // 262144
    float* h       = theta + 262144;   // 524288 (enc hidden)
    float* dh      = h + 524288;       // 262144 (dec hidden)
    float* rbuf    = dh + 262144;      // 1024
    float* scal    = rbuf + 1024;      // 8
    float* om_add  = scal + 8;         // 256
    float* partial = om_add + 256;     // 256*64
    float* rpart   = partial + 16384;  // 64
    unsigned short* W1t = (unsigned short*)(rpart + 64);                          // 512*512 bf16
    unsigned short* W2t = (unsigned short*)(rpart + 64 + 131072);                 // 512*256
    unsigned short* W3t = (unsigned short*)(rpart + 64 + 131072 + 65536);         // 512*256
    unsigned short* W4t = (unsigned short*)(rpart + 64 + 131072 + 65536 + 65536); // 256*128

    // weight prep + Sinkhorn (also initializes scal/om_add)
    prep_wt_kernel<<<136, 256, 0, stream>>>(eW1, eW2, dW1, dW2, W1t, W2t, W3t, W4t);
    sinkhorn_kernel<<<1, 1024, 0, stream>>>(exlog, P, scal, om_add);

    // encoder (MFMA bf16)
    gemm_mfma_kernel<1, 512, false><<<dim3(8, 16), 256, 0, stream>>>(x, W1t, eb1, h, 512);
    gemm_mfma_kernel<2, 512, false><<<dim3(4, 16), 256, 0, stream>>>(h, W2t, eb2, theta, 256);

    // layers (operator of layer li-1 applied in kuramoto prologue of layer li)
    for (int li = 0; li < 4; ++li) {
        kuramoto_mfma_kernel<<<64, 1024, 0, stream>>>(theta, K + li * 65536, omega + li * 256,
                                                      Kg + li, scal, om_add, rbuf, rpart, P, li);
        sel_partial_kernel<<<256, 256, 0, stream>>>(theta, rbuf, rpart, scal, sW1, sb1,
                                                    zm, zd, partial);
        op_finalize_kernel<<<1, 256, 0, stream>>>(partial, sW2, sb2, opstr, cfreq, rpart,
                                                  zm, zd, scal, om_add);
    }

    // last layer's operator, then decoder (emb fused into MFMA GEMM1)
    apply_op_kernel<<<128, 256, 0, stream>>>(theta, P, rbuf, scal, 3);
    gemm_mfma_kernel<1, 512, true><<<dim3(4, 16), 256, 0, stream>>>(theta, W3t, db1, dh, 256);
    gemm_mfma_kernel<0, 256, false><<<dim3(2, 16), 256, 0, stream>>>(dh, W4t, db2, out, 128);

    (void)in_sizes; (void)n_in; (void)out_size; (void)ws_size;
}

// Round 17
// 202.522 us; speedup vs baseline: 2.1008x; 1.0559x over previous
//
#include <hip/hip_runtime.h>
#include <hip/hip_fp16.h>
#include <math.h>

#define DT_F 0.1f

typedef __attribute__((ext_vector_type(8))) short short8;
typedef __attribute__((ext_vector_type(4))) float f32x4;

// ---------------------------------------------------------------- helpers

__device__ __forceinline__ float gelu_f(float x) {
    return 0.5f * x * (1.0f + erff(x * 0.7071067811865475f));
}

__device__ __forceinline__ unsigned short f2bf_rne(float f) {
    union { float f; unsigned u; } v; v.f = f;
    unsigned x = v.u;
    unsigned r = x + 0x7fffu + ((x >> 16) & 1u);
    return (unsigned short)(r >> 16);
}

__device__ __forceinline__ unsigned rotl32(unsigned v, int d) {
    return (v << d) | (v >> (32 - d));
}

// JAX threefry2x32, 20 rounds
__device__ __forceinline__ void threefry2x32(unsigned k0, unsigned k1,
                                             unsigned x0, unsigned x1,
                                             unsigned& o0, unsigned& o1) {
    unsigned k2 = k0 ^ k1 ^ 0x1BD11BDAu;
    x0 += k0; x1 += k1;
    const int r0[4] = {13, 15, 26, 6};
    const int r1[4] = {17, 29, 16, 24};
#pragma unroll
    for (int g = 0; g < 5; ++g) {
        const int* R = (g & 1) ? r1 : r0;
#pragma unroll
        for (int q = 0; q < 4; ++q) { x0 += x1; x1 = rotl32(x1, R[q]); x1 ^= x0; }
        unsigned a, b;
        switch (g) {
            case 0:  a = k1; b = k2 + 1u; break;
            case 1:  a = k2; b = k0 + 2u; break;
            case 2:  a = k0; b = k1 + 3u; break;
            case 3:  a = k1; b = k2 + 4u; break;
            default: a = k2; b = k0 + 5u; break;
        }
        x0 += a; x1 += b;
    }
    o0 = x0; o1 = x1;
}

// XLA ErfInv32 (Giles polynomial)
__device__ __forceinline__ float erfinv_xla(float x) {
    float w = -log1pf(-x * x);
    float p;
    if (w < 5.0f) {
        w -= 2.5f;
        p = 2.81022636e-08f;
        p = fmaf(p, w, 3.43273939e-07f);
        p = fmaf(p, w, -3.5233877e-06f);
        p = fmaf(p, w, -4.39150654e-06f);
        p = fmaf(p, w, 0.00021858087f);
        p = fmaf(p, w, -0.00125372503f);
        p = fmaf(p, w, -0.00417768164f);
        p = fmaf(p, w, 0.246640727f);
        p = fmaf(p, w, 1.50140941f);
    } else {
        w = sqrtf(w) - 3.0f;
        p = -0.000200214257f;
        p = fmaf(p, w, 0.000100950558f);
        p = fmaf(p, w, 0.00134934322f);
        p = fmaf(p, w, -0.00367342844f);
        p = fmaf(p, w, 0.00573950773f);
        p = fmaf(p, w, -0.0076224613f);
        p = fmaf(p, w, 0.00943887047f);
        p = fmaf(p, w, 1.00167406f);
        p = fmaf(p, w, 2.83297682f);
    }
    return p * x;
}

// jax.random.normal(fold_in(key(42), li), (1024,256)) element at flat index
__device__ __forceinline__ float jax_normal_elem(unsigned fk0, unsigned fk1, unsigned flat) {
    const unsigned HALF = 131072u;  // 1024*256/2
    unsigned idx = (flat < HALF) ? flat : (flat - HALF);
    unsigned o0, o1;
    threefry2x32(fk0, fk1, idx, idx + HALF, o0, o1);
    unsigned bits = (flat < HALF) ? o0 : o1;
    float f = __uint_as_float((bits >> 9) | 0x3F800000u) - 1.0f;   // [0,1)
    const float LO = __uint_as_float(0xBF7FFFFFu);                  // -1 + 2^-24
    float u = fmaxf(LO, fmaf(f, 2.0f, LO));                         // maxval-minval == 2.0f exactly
    return 1.41421356237f * erfinv_xla(u);
}

// ---------------------------------------------------------------- weight transpose+bf16 prep

__global__ __launch_bounds__(256) void prep_wt_kernel(
    const float* __restrict__ W1, const float* __restrict__ W2,
    const float* __restrict__ W3, const float* __restrict__ W4,
    unsigned short* __restrict__ T1, unsigned short* __restrict__ T2,
    unsigned short* __restrict__ T3, unsigned short* __restrict__ T4)
{
    __shared__ float tile[64][65];
    int b = blockIdx.x;
    const float* W; unsigned short* T; int K, N, kt, nt;
    if (b < 64)       { W = W1; T = T1; K = 512; N = 512; kt = b >> 3; nt = b & 7; }
    else if (b < 96)  { b -= 64;  W = W2; T = T2; K = 512; N = 256; kt = b >> 2; nt = b & 3; }
    else if (b < 128) { b -= 96;  W = W3; T = T3; K = 512; N = 256; kt = b >> 2; nt = b & 3; }
    else              { b -= 128; W = W4; T = T4; K = 256; N = 128; kt = b >> 1; nt = b & 1; }
    const int k0 = kt * 64, n0 = nt * 64;
    const int t = threadIdx.x;

#pragma unroll
    for (int i = 0; i < 4; ++i) {
        int r = (t >> 4) + i * 16;
        int c = (t & 15) * 4;
        float4 v = *reinterpret_cast<const float4*>(&W[(k0 + r) * N + n0 + c]);
        tile[r][c] = v.x; tile[r][c + 1] = v.y; tile[r][c + 2] = v.z; tile[r][c + 3] = v.w;
    }
    __syncthreads();
#pragma unroll
    for (int i = 0; i < 4; ++i) {
        int nn = (t >> 4) + i * 16;
        int kc = (t & 15) * 4;
        ushort4 o;
        o.x = f2bf_rne(tile[kc + 0][nn]);
        o.y = f2bf_rne(tile[kc + 1][nn]);
        o.z = f2bf_rne(tile[kc + 2][nn]);
        o.w = f2bf_rne(tile[kc + 3][nn]);
        *reinterpret_cast<ushort4*>(&T[(n0 + nn) * K + k0 + kc]) = o;
    }
}

// ---------------------------------------------------------------- MFMA GEMM (bf16 inputs, f32 acc)

template <int ACT, int KF, bool EMB>
__global__ __launch_bounds__(256) void gemm_mfma_kernel(
    const float* __restrict__ A,
    const unsigned short* __restrict__ Wt,
    const float* __restrict__ bias,
    float* __restrict__ C, int N)
{
    constexpr int STR = KF + 8;
    __shared__ __align__(16) unsigned short A_s[64 * STR];
    __shared__ __align__(16) unsigned short B_s[64 * STR];
    const int tid = threadIdx.x;
    const int m_base = blockIdx.y * 64;
    const int n_base = blockIdx.x * 64;

    {
        constexpr int ITERS = 64 * KF / 2048;
#pragma unroll
        for (int c = 0; c < ITERS; ++c) {
            const int f = c * 2048 + tid * 8;
            const int row = f / KF, k = f % KF;
            float4 a0, a1;
            if (EMB) {
                const int kk = k & 255;
                a0 = *reinterpret_cast<const float4*>(&A[(m_base + row) * 256 + kk]);
                a1 = *reinterpret_cast<const float4*>(&A[(m_base + row) * 256 + kk + 4]);
                if (k < 256) {
                    a0.x = __cosf(a0.x); a0.y = __cosf(a0.y); a0.z = __cosf(a0.z); a0.w = __cosf(a0.w);
                    a1.x = __cosf(a1.x); a1.y = __cosf(a1.y); a1.z = __cosf(a1.z); a1.w = __cosf(a1.w);
                } else {
                    a0.x = __sinf(a0.x); a0.y = __sinf(a0.y); a0.z = __sinf(a0.z); a0.w = __sinf(a0.w);
                    a1.x = __sinf(a1.x); a1.y = __sinf(a1.y); a1.z = __sinf(a1.z); a1.w = __sinf(a1.w);
                }
            } else {
                a0 = *reinterpret_cast<const float4*>(&A[(m_base + row) * KF + k]);
                a1 = *reinterpret_cast<const float4*>(&A[(m_base + row) * KF + k + 4]);
            }
            short8 v;
            v[0] = (short)f2bf_rne(a0.x); v[1] = (short)f2bf_rne(a0.y);
            v[2] = (short)f2bf_rne(a0.z); v[3] = (short)f2bf_rne(a0.w);
            v[4] = (short)f2bf_rne(a1.x); v[5] = (short)f2bf_rne(a1.y);
            v[6] = (short)f2bf_rne(a1.z); v[7] = (short)f2bf_rne(a1.w);
            *reinterpret_cast<short8*>(&A_s[row * STR + k]) = v;
        }
    }
    {
        constexpr int ITERS = 64 * KF / 2048;
#pragma unroll
        for (int c = 0; c < ITERS; ++c) {
            const int f = c * 2048 + tid * 8;
            const int n = f / KF, k = f % KF;
            short8 v = *reinterpret_cast<const short8*>(&Wt[(n_base + n) * KF + k]);
            *reinterpret_cast<short8*>(&B_s[n * STR + k]) = v;
        }
    }
    __syncthreads();

    const int l = tid & 63, w = tid >> 6;
    const int lo = l & 15, hi = l >> 4;

    f32x4 acc0 = {0.f, 0.f, 0.f, 0.f};
    f32x4 acc1 = {0.f, 0.f, 0.f, 0.f};
    f32x4 acc2 = {0.f, 0.f, 0.f, 0.f};
    f32x4 acc3 = {0.f, 0.f, 0.f, 0.f};
#pragma unroll
    for (int kc = 0; kc < KF / 32; ++kc) {
        short8 af = *reinterpret_cast<const short8*>(&A_s[(w * 16 + lo) * STR + kc * 32 + hi * 8]);
        short8 b0 = *reinterpret_cast<const short8*>(&B_s[(0 * 16 + lo) * STR + kc * 32 + hi * 8]);
        short8 b1 = *reinterpret_cast<const short8*>(&B_s[(1 * 16 + lo) * STR + kc * 32 + hi * 8]);
        short8 b2 = *reinterpret_cast<const short8*>(&B_s[(2 * 16 + lo) * STR + kc * 32 + hi * 8]);
        short8 b3 = *reinterpret_cast<const short8*>(&B_s[(3 * 16 + lo) * STR + kc * 32 + hi * 8]);
        acc0 = __builtin_amdgcn_mfma_f32_16x16x32_bf16(af, b0, acc0, 0, 0, 0);
        acc1 = __builtin_amdgcn_mfma_f32_16x16x32_bf16(af, b1, acc1, 0, 0, 0);
        acc2 = __builtin_amdgcn_mfma_f32_16x16x32_bf16(af, b2, acc2, 0, 0, 0);
        acc3 = __builtin_amdgcn_mfma_f32_16x16x32_bf16(af, b3, acc3, 0, 0, 0);
    }

#pragma unroll
    for (int nf = 0; nf < 4; ++nf) {
        const f32x4 a = (nf == 0) ? acc0 : (nf == 1) ? acc1 : (nf == 2) ? acc2 : acc3;
        const int n = n_base + nf * 16 + lo;
        const float bv = bias[n];
#pragma unroll
        for (int q = 0; q < 4; ++q) {
            const int m = m_base + w * 16 + hi * 4 + q;
            float v = a[q] + bv;
            if (ACT == 1) v = gelu_f(v);
            else if (ACT == 2) v = tanhf(v) * 3.14159274101257324f;
            C[m * N + n] = v;
        }
    }
}

// ---------------------------------------------------------------- Sinkhorn (multiplicative, fp16 E in LDS)
// Also initializes zbuf[0] = 0.1.

__global__ __launch_bounds__(1024) void sinkhorn_kernel(const float* __restrict__ logits,
                                                        float* __restrict__ P,
                                                        float* __restrict__ zbuf) {
    __shared__ __align__(16) __half Eh[256][260];
    __shared__ float a[256], b[256];
    __shared__ float part[8][256];
    const int t = threadIdx.x;

    if (t == 0) zbuf[0] = 0.1f;
    if (t < 256) b[t] = 1.0f;

    {
        const int r = t >> 2, c0 = (t & 3) * 64;
#pragma unroll
        for (int j = 0; j < 64; j += 4) {
            float4 x4 = *reinterpret_cast<const float4*>(&logits[r * 256 + c0 + j]);
            __half2 h01 = __floats2half2_rn(__expf(x4.x), __expf(x4.y));
            __half2 h23 = __floats2half2_rn(__expf(x4.z), __expf(x4.w));
            *reinterpret_cast<__half2*>(&Eh[r][c0 + j])     = h01;
            *reinterpret_cast<__half2*>(&Eh[r][c0 + j + 2]) = h23;
        }
    }
    __syncthreads();

    for (int it = 0; it < 5; ++it) {
        {
            const int i = t & 255, q = t >> 8;
            float s0 = 0.f, s1 = 0.f, s2 = 0.f, s3 = 0.f;
#pragma unroll
            for (int j0 = 0; j0 < 64; j0 += 4) {
                float2 e4 = *reinterpret_cast<const float2*>(&Eh[i][q * 64 + j0]);
                const __half2* hp = reinterpret_cast<const __half2*>(&e4);
                float2 f01 = __half22float2(hp[0]);
                float2 f23 = __half22float2(hp[1]);
                float4 bv = *reinterpret_cast<const float4*>(&b[q * 64 + j0]);
                s0 = fmaf(f01.x, bv.x, s0);
                s1 = fmaf(f01.y, bv.y, s1);
                s2 = fmaf(f23.x, bv.z, s2);
                s3 = fmaf(f23.y, bv.w, s3);
            }
            part[q][i] = (s0 + s1) + (s2 + s3);
        }
        __syncthreads();
        if (t < 256) a[t] = 1.0f / (part[0][t] + part[1][t] + part[2][t] + part[3][t]);
        __syncthreads();
        {
            const int jp = t & 127, seg = t >> 7;
            float s0 = 0.f, s1 = 0.f;
#pragma unroll
            for (int i0 = 0; i0 < 32; i0 += 4) {
                float4 av = *reinterpret_cast<const float4*>(&a[seg * 32 + i0]);
                __half2 e0 = *reinterpret_cast<const __half2*>(&Eh[seg * 32 + i0 + 0][2 * jp]);
                __half2 e1 = *reinterpret_cast<const __half2*>(&Eh[seg * 32 + i0 + 1][2 * jp]);
                __half2 e2 = *reinterpret_cast<const __half2*>(&Eh[seg * 32 + i0 + 2][2 * jp]);
                __half2 e3 = *reinterpret_cast<const __half2*>(&Eh[seg * 32 + i0 + 3][2 * jp]);
                float2 f0 = __half22float2(e0), f1 = __half22float2(e1);
                float2 f2 = __half22float2(e2), f3 = __half22float2(e3);
                s0 = fmaf(f0.x, av.x, s0); s1 = fmaf(f0.y, av.x, s1);
                s0 = fmaf(f1.x, av.y, s0); s1 = fmaf(f1.y, av.y, s1);
                s0 = fmaf(f2.x, av.z, s0); s1 = fmaf(f2.y, av.z, s1);
                s0 = fmaf(f3.x, av.w, s0); s1 = fmaf(f3.y, av.w, s1);
            }
            part[seg][2 * jp]     = s0;
            part[seg][2 * jp + 1] = s1;
        }
        __syncthreads();
        if (t < 256) {
            float s = ((part[0][t] + part[1][t]) + (part[2][t] + part[3][t]))
                    + ((part[4][t] + part[5][t]) + (part[6][t] + part[7][t]));
            b[t] = 1.0f / s;
        }
        __syncthreads();
    }

    {
        const int r = t >> 2, c0 = (t & 3) * 64;
        const float ar = a[r];
#pragma unroll
        for (int j = 0; j < 64; j += 4) {
            float2 e4 = *reinterpret_cast<const float2*>(&Eh[r][c0 + j]);
            const __half2* hp = reinterpret_cast<const __half2*>(&e4);
            float2 f01 = __half22float2(hp[0]);
            float2 f23 = __half22float2(hp[1]);
            float4 bv = *reinterpret_cast<const float4*>(&b[c0 + j]);
            float4 o;
            o.x = f01.x * ar * bv.x;
            o.y = f01.y * ar * bv.y;
            o.z = f23.x * ar * bv.z;
            o.w = f23.y * ar * bv.w;
            *reinterpret_cast<float4*>(&P[r * 256 + c0 + j]) = o;
        }
    }
}

// ---------------------------------------------------------------- Kuramoto layer via MFMA
// 64 blocks x 512 threads; block owns 16 batch rows. Double-buffered sin/cos
// (ONE barrier/step). For li>0 the prologue REDUNDANTLY recomputes layer li-1's
// finalize (rmean/hbar/op/sm/kmult) from partial/rpart_prev -- identical
// arithmetic in every block, visibility by stream order, no fences. Commits
// zbuf[li] = f(zbuf[li-1], rmean) (all blocks write the same value).

__global__ __launch_bounds__(512) void kuramoto_mfma_kernel(
    float* __restrict__ theta,
    const float* __restrict__ Kl,
    const float* __restrict__ omega_l,
    const float* __restrict__ Kg_p,
    const float* __restrict__ P,
    const float* __restrict__ rpart_prev,
    float* __restrict__ rpart_cur,
    const float* __restrict__ rbuf_prev,
    float* __restrict__ rbuf_cur,
    const float* __restrict__ partial,
    const float* __restrict__ sW2,
    const float* __restrict__ sb2,
    const float* __restrict__ opstr,
    const float* __restrict__ cf,
    const float* __restrict__ zm_p,
    const float* __restrict__ zd_p,
    float* __restrict__ zbuf,
    int li)
{
    __shared__ __align__(16) unsigned short s_lds[2][16][264];
    __shared__ __align__(16) unsigned short c_lds[2][16][264];
    __shared__ __align__(16) float th_lds[16][260];
    __shared__ float rp_s[16][128];
    __shared__ float rp_c[16][128];
    __shared__ float red_s[16][32];
    __shared__ float red_c[16][32];
    __shared__ float rloc[16];
    __shared__ float red4[4][64];
    __shared__ float hbar_s[64];
    __shared__ float lgs[6];
    __shared__ float s_rmean;

    const int tid = threadIdx.x;
    const int l  = tid & 63;
    const int w  = tid >> 6;
    const int lo = l & 15;
    const int hi = l >> 4;
    const int cb = w * 32;
    const int r0 = blockIdx.x * 16;

    // ---- stage theta rows to LDS (coalesced) ----------------------------
    {
        const int row = tid >> 5;
        const int c0 = (tid & 31) * 8;
        float4 a = *reinterpret_cast<const float4*>(&theta[(r0 + row) * 256 + c0]);
        float4 b = *reinterpret_cast<const float4*>(&theta[(r0 + row) * 256 + c0 + 4]);
        *reinterpret_cast<float4*>(&th_lds[row][c0])     = a;
        *reinterpret_cast<float4*>(&th_lds[row][c0 + 4]) = b;
    }

    // ---- redundant finalize of layer li-1 (bit-identical to old kernel) --
    int op_c = 0;
    float sm_c = 0.0f, km_c = 1.0f, opv_c = 0.0f;
    if (li > 0) {
        if (tid < 64) {
            float s = rpart_prev[tid];
#pragma unroll
            for (int off = 32; off > 0; off >>= 1) s += __shfl_down(s, off);
            if (tid == 0) s_rmean = s * (1.0f / 1024.0f);
        }
        if (tid < 256) {
            const int h = tid & 63, q = tid >> 6;
            float s = 0.0f;
#pragma unroll 8
            for (int bb = q * 64; bb < q * 64 + 64; ++bb) s += partial[bb * 64 + h];
            red4[q][h] = s;
        }
        __syncthreads();
        if (tid < 64)
            hbar_s[tid] = (red4[0][tid] + red4[1][tid] + red4[2][tid] + red4[3][tid])
                        * (1.0f / 1024.0f);
        __syncthreads();
        if (tid < 6) {
            float lv = sb2[tid];
            for (int hh = 0; hh < 64; ++hh) lv = fmaf(hbar_s[hh], sW2[hh * 6 + tid], lv);
            lgs[tid] = lv;
        }
        __syncthreads();
        {
            float best = -1e30f;
#pragma unroll
            for (int o = 0; o < 6; ++o) {
                if (lgs[o] > best) { best = lgs[o]; op_c = o; }
            }
            const float rmean = s_rmean;
            opv_c = opstr[op_c];
            sm_c  = opv_c * rmean;
            km_c  = (op_c == 1) ? (1.0f + sm_c * 0.5f)
                  : (op_c == 2) ? (1.0f - sm_c * 0.3f) : 1.0f;
            if (tid == 0) {
                float zp = zbuf[li - 1];
                float dz = (*zm_p) * (rmean - zp) - (*zd_p) * (zp - 0.5f);
                zbuf[li] = fminf(fmaxf(zp + 0.01f * dz, 0.0f), 1.0f);
            }
        }
    }

    // ---- K fragments (registers, bf16) via symmetry ---------------------
    short8 kfrag[8][2];
#pragma unroll
    for (int nf = 0; nf < 2; ++nf) {
        const int col = cb + nf * 16 + lo;
        const float* krow = Kl + col * 256;
#pragma unroll
        for (int ks = 0; ks < 8; ++ks) {
            const int kb = ks * 32 + hi * 8;
            float4 k0 = *reinterpret_cast<const float4*>(&krow[kb]);
            float4 k1 = *reinterpret_cast<const float4*>(&krow[kb + 4]);
            short8 f;
            f[0] = (short)f2bf_rne(k0.x); f[1] = (short)f2bf_rne(k0.y);
            f[2] = (short)f2bf_rne(k0.z); f[3] = (short)f2bf_rne(k0.w);
            f[4] = (short)f2bf_rne(k1.x); f[5] = (short)f2bf_rne(k1.y);
            f[6] = (short)f2bf_rne(k1.z); f[7] = (short)f2bf_rne(k1.w);
            kfrag[ks][nf] = f;
        }
    }
    __syncthreads();

    const float gk = Kg_p[0] * (1.0f / 256.0f) * km_c;

    // ---- apply previous operator + pick up theta in MFMA C/D layout -----
    float t[2][4];
    if (op_c == 3) {
        float acc[2][4] = {};
        for (int j = 0; j < 256; ++j) {
            float p0 = P[j * 256 + cb + lo];
            float p1 = P[j * 256 + cb + 16 + lo];
#pragma unroll
            for (int q = 0; q < 4; ++q) {
                float tv = th_lds[hi * 4 + q][j];
                acc[0][q] = fmaf(tv, p0, acc[0][q]);
                acc[1][q] = fmaf(tv, p1, acc[1][q]);
            }
        }
#pragma unroll
        for (int nf = 0; nf < 2; ++nf)
#pragma unroll
            for (int q = 0; q < 4; ++q) t[nf][q] = acc[nf][q];
    } else {
#pragma unroll
        for (int nf = 0; nf < 2; ++nf)
#pragma unroll
            for (int q = 0; q < 4; ++q)
                t[nf][q] = th_lds[hi * 4 + q][cb + nf * 16 + lo];
        if (op_c == 4) {
            unsigned fk0, fk1;
            threefry2x32(0u, 42u, 0u, (unsigned)(li - 1), fk0, fk1);
#pragma unroll
            for (int nf = 0; nf < 2; ++nf)
#pragma unroll
                for (int q = 0; q < 4; ++q) {
                    const int row = hi * 4 + q;
                    const int col = cb + nf * 16 + lo;
                    unsigned flat = (unsigned)((r0 + row) * 256 + col);
                    float nz = jax_normal_elem(fk0, fk1, flat);
                    t[nf][q] += nz * opv_c * rbuf_prev[r0 + row] * 0.2f;
                }
        }
    }

    // ---- initial sincos staging -----------------------------------------
    float si[2][4], ci[2][4];
    float om[2];
#pragma unroll
    for (int nf = 0; nf < 2; ++nf) {
        const int col = cb + nf * 16 + lo;
        om[nf] = omega_l[col] + ((op_c == 5) ? cf[col] * sm_c : 0.0f);
#pragma unroll
        for (int q = 0; q < 4; ++q) {
            const int row = hi * 4 + q;
            float sv, cv;
            __sincosf(t[nf][q], &sv, &cv);
            si[nf][q] = sv; ci[nf][q] = cv;
            s_lds[0][row][col] = f2bf_rne(sv);
            c_lds[0][row][col] = f2bf_rne(cv);
        }
    }
    __syncthreads();

    // ---- 10 steps, ONE barrier each (double-buffered sin/cos) -------------
    int cur = 0;
    for (int s = 0; s < 10; ++s) {
        f32x4 accS0 = {0.f, 0.f, 0.f, 0.f};
        f32x4 accS1 = {0.f, 0.f, 0.f, 0.f};
        f32x4 accC0 = {0.f, 0.f, 0.f, 0.f};
        f32x4 accC1 = {0.f, 0.f, 0.f, 0.f};
#pragma unroll
        for (int ks = 0; ks < 8; ++ks) {
            short8 aS = *reinterpret_cast<const short8*>(&s_lds[cur][lo][ks * 32 + hi * 8]);
            short8 aC = *reinterpret_cast<const short8*>(&c_lds[cur][lo][ks * 32 + hi * 8]);
            accS0 = __builtin_amdgcn_mfma_f32_16x16x32_bf16(aS, kfrag[ks][0], accS0, 0, 0, 0);
            accS1 = __builtin_amdgcn_mfma_f32_16x16x32_bf16(aS, kfrag[ks][1], accS1, 0, 0, 0);
            accC0 = __builtin_amdgcn_mfma_f32_16x16x32_bf16(aC, kfrag[ks][0], accC0, 0, 0, 0);
            accC1 = __builtin_amdgcn_mfma_f32_16x16x32_bf16(aC, kfrag[ks][1], accC1, 0, 0, 0);
        }
        const int nxt = cur ^ 1;
#pragma unroll
        for (int nf = 0; nf < 2; ++nf) {
#pragma unroll
            for (int q = 0; q < 4; ++q) {
                float aS = (nf == 0) ? accS0[q] : accS1[q];
                float aC = (nf == 0) ? accC0[q] : accC1[q];
                float coup = ci[nf][q] * aS - si[nf][q] * aC;
                float tn = t[nf][q] + DT_F * (om[nf] + gk * coup);
                t[nf][q] = tn;
                float sv, cv;
                __sincosf(tn, &sv, &cv);
                si[nf][q] = sv; ci[nf][q] = cv;
                const int row = hi * 4 + q;
                const int col = cb + nf * 16 + lo;
                s_lds[nxt][row][col] = f2bf_rne(sv);
                c_lds[nxt][row][col] = f2bf_rne(cv);
            }
        }
        __syncthreads();
        cur = nxt;
    }

#pragma unroll
    for (int q = 0; q < 4; ++q) {
        const int row = hi * 4 + q;
        rp_s[row][w * 16 + lo] = si[0][q] + si[1][q];
        rp_c[row][w * 16 + lo] = ci[0][q] + ci[1][q];
    }
#pragma unroll
    for (int nf = 0; nf < 2; ++nf) {
#pragma unroll
        for (int q = 0; q < 4; ++q) {
            const int row = hi * 4 + q;
            const int col = cb + nf * 16 + lo;
            theta[(r0 + row) * 256 + col] = atan2f(si[nf][q], ci[nf][q]);
        }
    }
    __syncthreads();

    {
        const int row = tid >> 5;
        const int i = tid & 31;
        float ssum = rp_s[row][i] + rp_s[row][i + 32] + rp_s[row][i + 64] + rp_s[row][i + 96];
        float csum = rp_c[row][i] + rp_c[row][i + 32] + rp_c[row][i + 64] + rp_c[row][i + 96];
        red_s[row][i] = ssum;
        red_c[row][i] = csum;
        __syncthreads();
#pragma unroll
        for (int off = 16; off > 0; off >>= 1) {
            if (i < off) {
                red_s[row][i] += red_s[row][i + off];
                red_c[row][i] += red_c[row][i + off];
            }
            __syncthreads();
        }
        if (i == 0) {
            float sm = red_s[row][0] * (1.0f / 256.0f);
            float cm = red_c[row][0] * (1.0f / 256.0f);
            float rv = sqrtf(cm * cm + sm * sm);
            rbuf_cur[r0 + row] = rv;
            rloc[row] = rv;
        }
        __syncthreads();
        if (tid == 0) {
            float s = 0.0f;
#pragma unroll
            for (int rr = 0; rr < 16; ++rr) s += rloc[rr];
            rpart_cur[blockIdx.x] = s;
        }
    }
}

// ---------------------------------------------------------------- selection MLP (z computed from zbuf[li])

__global__ __launch_bounds__(256) void sel_partial_kernel(const float* __restrict__ theta,
                                                          const float* __restrict__ rbuf,
                                                          const float* __restrict__ rpart,
                                                          const float* __restrict__ zbuf,
                                                          const float* __restrict__ W1,
                                                          const float* __restrict__ b1,
                                                          const float* __restrict__ zm_p,
                                                          const float* __restrict__ zd_p,
                                                          float* __restrict__ partial,
                                                          int li) {
    __shared__ float Wt[64][261];
    __shared__ float th_s[4][256];
    __shared__ float gl[4][64];
    __shared__ float s_z;
    const int t = threadIdx.x;
    const int h = t & 63;
    const int rr = t >> 6;
    const int blk = blockIdx.x;

    if (t < 64) {
        float s = rpart[t];
#pragma unroll
        for (int off = 32; off > 0; off >>= 1) s += __shfl_down(s, off);
        if (t == 0) {
            float rmean = s * (1.0f / 1024.0f);
            float zp = zbuf[li];
            float dz = (*zm_p) * (rmean - zp) - (*zd_p) * (zp - 0.5f);
            float zn = zp + 0.01f * dz;
            s_z = fminf(fmaxf(zn, 0.0f), 1.0f);
        }
    }

    for (int idx = t; idx < 258 * 64; idx += 256)
        Wt[idx & 63][idx >> 6] = W1[idx];

    {
        const int c0 = h * 4;
        float4 v = *reinterpret_cast<const float4*>(&theta[(blk * 4 + rr) * 256 + c0]);
        *reinterpret_cast<float4*>(&th_s[rr][c0]) = v;
    }
    __syncthreads();

    const float z = s_z;
    float d0 = 0.f, d1 = 0.f, d2 = 0.f, d3 = 0.f;
#pragma unroll 4
    for (int k0 = 0; k0 < 256; k0 += 4) {
        float4 tv = *reinterpret_cast<const float4*>(&th_s[rr][k0]);
        d0 = fmaf(tv.x, Wt[h][k0 + 0], d0);
        d1 = fmaf(tv.y, Wt[h][k0 + 1], d1);
        d2 = fmaf(tv.z, Wt[h][k0 + 2], d2);
        d3 = fmaf(tv.w, Wt[h][k0 + 3], d3);
    }
    float full = (d0 + d1) + (d2 + d3) + b1[h]
               + rbuf[blk * 4 + rr] * Wt[h][256] + z * Wt[h][257];
    gl[rr][h] = gelu_f(full);
    __syncthreads();
    if (t < 64) partial[blk * 64 + t] = ((gl[0][t] + gl[1][t]) + gl[2][t]) + gl[3][t];
}

// ---------------------------------------------------------------- standalone apply (layer 3's op)
// Redundantly recomputes the layer-3 finalize (same grouping as before).

__global__ __launch_bounds__(256) void apply_op_kernel(float* __restrict__ theta,
                                                       const float* __restrict__ P,
                                                       const float* __restrict__ r,
                                                       const float* __restrict__ rpart,
                                                       const float* __restrict__ partial,
                                                       const float* __restrict__ sW2,
                                                       const float* __restrict__ sb2,
                                                       const float* __restrict__ opstr,
                                                       int li) {
    __shared__ float th[8][256];
    __shared__ float red4[4][64];
    __shared__ float hbar_s[64];
    __shared__ float lgs[6];
    __shared__ float s_rmean;
    const int i = threadIdx.x;
    const int b0 = blockIdx.x * 8;

    // ---- redundant finalize ----
    if (i < 64) {
        float s = rpart[i];
#pragma unroll
        for (int off = 32; off > 0; off >>= 1) s += __shfl_down(s, off);
        if (i == 0) s_rmean = s * (1.0f / 1024.0f);
    }
    {
        const int h = i & 63, q = i >> 6;
        float s = 0.0f;
#pragma unroll 8
        for (int bb = q * 64; bb < q * 64 + 64; ++bb) s += partial[bb * 64 + h];
        red4[q][h] = s;
    }
    __syncthreads();
    if (i < 64)
        hbar_s[i] = (red4[0][i] + red4[1][i] + red4[2][i] + red4[3][i]) * (1.0f / 1024.0f);
    __syncthreads();
    if (i < 6) {
        float lv = sb2[i];
        for (int hh = 0; hh < 64; ++hh) lv = fmaf(hbar_s[hh], sW2[hh * 6 + i], lv);
        lgs[i] = lv;
    }
    __syncthreads();
    int op = 0;
    {
        float best = -1e30f;
#pragma unroll
        for (int o = 0; o < 6; ++o) {
            if (lgs[o] > best) { best = lgs[o]; op = o; }
        }
    }
    const float opv = opstr[op];

    if (op == 3) {
#pragma unroll
        for (int rr = 0; rr < 8; ++rr) th[rr][i] = theta[(b0 + rr) * 256 + i];
        __syncthreads();
        float acc[8] = {0.f, 0.f, 0.f, 0.f, 0.f, 0.f, 0.f, 0.f};
        for (int j = 0; j < 256; ++j) {
            float pv = P[j * 256 + i];
#pragma unroll
            for (int rr = 0; rr < 8; ++rr) acc[rr] = fmaf(th[rr][j], pv, acc[rr]);
        }
#pragma unroll
        for (int rr = 0; rr < 8; ++rr) theta[(b0 + rr) * 256 + i] = acc[rr];
    } else if (op == 4) {
        unsigned fk0, fk1;
        threefry2x32(0u, 42u, 0u, (unsigned)li, fk0, fk1);
#pragma unroll
        for (int rr = 0; rr < 8; ++rr) {
            int b = b0 + rr;
            unsigned flat = (unsigned)(b * 256 + i);
            float nz = jax_normal_elem(fk0, fk1, flat);
            float strength = opv * r[b];
            theta[b * 256 + i] += nz * strength * 0.2f;
        }
    }
}

// ---------------------------------------------------------------- launch

extern "C" void kernel_launch(void* const* d_in, const int* in_sizes, int n_in,
                              void* d_out, int out_size, void* d_ws, size_t ws_size,
                              hipStream_t stream) {
    const float* x     = (const float*)d_in[0];
    const float* eW1   = (const float*)d_in[1];
    const float* eb1   = (const float*)d_in[2];
    const float* eW2   = (const float*)d_in[3];
    const float* eb2   = (const float*)d_in[4];
    const float* K     = (const float*)d_in[5];
    const float* omega = (const float*)d_in[6];
    const float* Kg    = (const float*)d_in[7];
    const float* opstr = (const float*)d_in[8];
    const float* exlog = (const float*)d_in[9];
    const float* cfreq = (const float*)d_in[10];
    const float* sW1   = (const float*)d_in[11];
    const float* sb1   = (const float*)d_in[12];
    const float* sW2   = (const float*)d_in[13];
    const float* sb2   = (const float*)d_in[14];
    const float* dW1   = (const float*)d_in[15];
    const float* db1   = (const float*)d_in[16];
    const float* dW2   = (const float*)d_in[17];
    const float* db2   = (const float*)d_in[18];
    const float* zm    = (const float*)d_in[19];
    const float* zd    = (const float*)d_in[20];
    float* out = (float*)d_out;

    float* ws       = (float*)d_ws;
    float* P        = ws;                 // 65536
    float* theta    = P + 65536;          // 262144
    float* h        = theta + 262144;     // 524288 (enc hidden)
    float* dh       = h + 524288;         // 262144 (dec hidden)
    float* rbuf2    = dh + 262144;        // 2*1024
    float* rpart2   = rbuf2 + 2048;       // 2*64
    float* partial  = rpart2 + 128;       // 256*64
    float* zbuf     = partial + 16384;    // 8
    unsigned short* W1t = (unsigned short*)(zbuf + 8);      // 512*512 bf16
    unsigned short* W2t = W1t + 262144;                      // 512*256
    unsigned short* W3t = W2t + 131072;                      // 512*256
    unsigned short* W4t = W3t + 131072;                      // 256*128

    // weight prep + Sinkhorn (also inits zbuf[0])
    prep_wt_kernel<<<136, 256, 0, stream>>>(eW1, eW2, dW1, dW2, W1t, W2t, W3t, W4t);
    sinkhorn_kernel<<<1, 1024, 0, stream>>>(exlog, P, zbuf);

    // encoder (MFMA bf16)
    gemm_mfma_kernel<1, 512, false><<<dim3(8, 16), 256, 0, stream>>>(x, W1t, eb1, h, 512);
    gemm_mfma_kernel<2, 512, false><<<dim3(4, 16), 256, 0, stream>>>(h, W2t, eb2, theta, 256);

    // layers: kuramoto (with folded finalize of li-1) + sel MLP
    for (int li = 0; li < 4; ++li) {
        const int pc = li & 1, pp = (li - 1) & 1;
        kuramoto_mfma_kernel<<<64, 512, 0, stream>>>(
            theta, K + li * 65536, omega + li * 256, Kg + li, P,
            rpart2 + pp * 64, rpart2 + pc * 64,
            rbuf2 + pp * 1024, rbuf2 + pc * 1024,
            partial, sW2, sb2, opstr, cfreq, zm, zd, zbuf, li);
        sel_partial_kernel<<<256, 256, 0, stream>>>(
            theta, rbuf2 + pc * 1024, rpart2 + pc * 64, zbuf,
            sW1, sb1, zm, zd, partial, li);
    }

    // layer 3's operator (folded finalize), then decoder (emb fused)
    apply_op_kernel<<<128, 256, 0, stream>>>(theta, P, rbuf2 + 1024, rpart2 + 64,
                                             partial, sW2, sb2, opstr, 3);
    gemm_mfma_kernel<1, 512, true><<<dim3(4, 16), 256, 0, stream>>>(theta, W3t, db1, dh, 256);
    gemm_mfma_kernel<0, 256, false><<<dim3(2, 16), 256, 0, stream>>>(dh, W4t, db2, out, 128);

    (void)in_sizes; (void)n_in; (void)out_size; (void)ws_size;
}